// Round 12
// baseline (267.095 us; speedup 1.0000x reference)
//
#include <hip/hip_runtime.h>
#include <math.h>

typedef unsigned short u16;
typedef unsigned int u32;

using f32x4 = __attribute__((ext_vector_type(4))) float;
using s16x8 = __attribute__((ext_vector_type(8))) short;
using f16x8 = __attribute__((ext_vector_type(8))) _Float16;
using u32x4 = __attribute__((ext_vector_type(4))) u32;

#define DEVI static __device__ __forceinline__

// ---- problem constants ----
#define BB 16
#define TT 512
#define TS 512
#define HH 1024
#define OO 1024

// bf16 split: x = hi + lo + eps, |eps| <= 2^-16 |x|
DEVI void split_bf(float x, u16& hb, u16& lb) {
    u32 xb = __float_as_uint(x);
    float hf = __uint_as_float(xb & 0xffff0000u);
    hb = (u16)(xb >> 16);
    lb = (u16)(__float_as_uint(x - hf) >> 16);
}

DEVI float ub(u16 h) { return __uint_as_float((u32)h << 16); }

template <int PREC> struct FragT;
template <> struct FragT<0> { using T = s16x8; };
template <> struct FragT<1> { using T = f16x8; };

DEVI f32x4 mfma16(s16x8 a, s16x8 b, f32x4 c) {
    return __builtin_amdgcn_mfma_f32_16x16x32_bf16(a, b, c, 0, 0, 0);
}
DEVI f32x4 mfma16(f16x8 a, f16x8 b, f32x4 c) {
    return __builtin_amdgcn_mfma_f32_16x16x32_f16(a, b, c, 0, 0, 0);
}

// async global->LDS, 16B/lane; LDS dest wave-uniform base + lane*16
DEVI void gl16(const void* g, void* l) {
    __builtin_amdgcn_global_load_lds(
        (__attribute__((address_space(1))) const void*)g,
        (__attribute__((address_space(3))) void*)l, 16, 0, 0);
}

// ============ fused prep 1: hs_prep (8192 blocks) | WaT transpose (1024) | lens (16) ============
__global__ void prep1_kernel(const float* __restrict__ hs,
                             u16* __restrict__ rhi, u16* __restrict__ rlo,
                             u16* __restrict__ thi,
                             const float* __restrict__ Wa,
                             u16* __restrict__ whi, u16* __restrict__ wlo,
                             const int* __restrict__ src, int* __restrict__ lens) {
    __shared__ float tile[32][33];
    __shared__ int part[4];
    int id = blockIdx.x;
    int tid = threadIdx.x;
    int tx = tid & 31, ty = tid >> 5;  // 32 x 8
    if (id < 8192) {
        int bx = id & 31, by = (id >> 5) & 15, bz = id >> 9;
        long boff = (long)bz * TS * HH;
        const float* s = hs + boff;
        u16* rh = rhi + boff;
        u16* rl = rlo + boff;
        u16* th = thi + boff;
        int c0 = bx * 32, r0 = by * 32;
#pragma unroll
        for (int i = 0; i < 32; i += 8) {
            long o = (long)(r0 + ty + i) * HH + (c0 + tx);
            float v = s[o];
            tile[ty + i][tx] = v;
            u16 hb, lb;
            split_bf(v, hb, lb);
            rh[o] = hb;
            rl[o] = lb;
        }
        __syncthreads();
#pragma unroll
        for (int i = 0; i < 32; i += 8) {
            long o = (long)(c0 + ty + i) * TS + (r0 + tx);
            th[o] = __builtin_bit_cast(u16, (_Float16)tile[tx][ty + i]);
        }
    } else if (id < 8192 + 1024) {
        int id2 = id - 8192;
        int bx = id2 & 31, by = id2 >> 5;
        int c0 = bx * 32, r0 = by * 32;
#pragma unroll
        for (int i = 0; i < 32; i += 8)
            tile[ty + i][tx] = Wa[(long)(r0 + ty + i) * HH + (c0 + tx)];
        __syncthreads();
#pragma unroll
        for (int i = 0; i < 32; i += 8) {
            u16 hb, lb;
            split_bf(tile[tx][ty + i], hb, lb);
            long o = (long)(c0 + ty + i) * HH + (r0 + tx);
            whi[o] = hb;
            wlo[o] = lb;
        }
    } else {
        int b = id - (8192 + 1024);
        int v0 = (src[b * TS + tid] != 0) ? 1 : 0;
        int v1 = (src[b * TS + 256 + tid] != 0) ? 1 : 0;
        unsigned long long m0 = __ballot(v0);
        unsigned long long m1 = __ballot(v1);
        if ((tid & 63) == 0) part[tid >> 6] = __popcll(m0) + __popcll(m1);
        __syncthreads();
        if (tid == 0) lens[b] = part[0] + part[1] + part[2] + part[3];
    }
}

// ============ fused prep 2: htF f16 (4096 blocks) | WcT f16 transpose (2048) ============
__global__ void prep2_kernel(const float* __restrict__ ht, u16* __restrict__ htF,
                             const float* __restrict__ Wc, u16* __restrict__ wcthi) {
    __shared__ float tile[32][33];
    int id = blockIdx.x;
    int tid = threadIdx.x;
    if (id < 4096) {
        long i = ((long)id * 256 + tid) * 8;
        float4 v0 = *(const float4*)(ht + i);
        float4 v1 = *(const float4*)(ht + i + 4);
        float fv[8] = {v0.x, v0.y, v0.z, v0.w, v1.x, v1.y, v1.z, v1.w};
        f16x8 o;
#pragma unroll
        for (int j = 0; j < 8; ++j) o[j] = (_Float16)fv[j];
        *(f16x8*)(htF + i) = o;
    } else {
        int id2 = id - 4096;
        int bx = id2 & 31, by = id2 >> 5;
        int tx = tid & 31, ty = tid >> 5;
        int c0 = bx * 32, r0 = by * 32;
#pragma unroll
        for (int i = 0; i < 32; i += 8)
            tile[ty + i][tx] = Wc[(long)(r0 + ty + i) * OO + (c0 + tx)];
        __syncthreads();
#pragma unroll
        for (int i = 0; i < 32; i += 8) {
            long o = (long)(c0 + ty + i) * (2 * HH) + (r0 + tx);
            wcthi[o] = __builtin_bit_cast(u16, (_Float16)tile[tx][ty + i]);
        }
    }
}

// masked softmax: full score = (h0+l0)+(h1+l1) bf16 parts, 1 wave/row.
__global__ void softmax_mask_kernel(u16* __restrict__ h0, u16* __restrict__ l0,
                                    const u16* __restrict__ h1, const u16* __restrict__ l1,
                                    const int* __restrict__ lens) {
    long row = blockIdx.x;
    int len = lens[blockIdx.x >> 9];
    int lane = threadIdx.x;
    long o = row * TS + 8 * lane;
    s16x8 vh0 = *(const s16x8*)(h0 + o);
    s16x8 vl0 = *(const s16x8*)(l0 + o);
    s16x8 vh1 = *(const s16x8*)(h1 + o);
    s16x8 vl1 = *(const s16x8*)(l1 + o);
    float f[8];
#pragma unroll
    for (int i = 0; i < 8; ++i)
        f[i] = (ub((u16)vh0[i]) + ub((u16)vl0[i])) + (ub((u16)vh1[i]) + ub((u16)vl1[i]));
    float m = f[0];
#pragma unroll
    for (int i = 1; i < 8; ++i) m = fmaxf(m, f[i]);
#pragma unroll
    for (int os = 32; os > 0; os >>= 1) m = fmaxf(m, __shfl_xor(m, os));
    float e[8];
    float sum = 0.f;
#pragma unroll
    for (int i = 0; i < 8; ++i) {
        e[i] = (8 * lane + i < len) ? expf(f[i] - m) : 0.f;
        sum += e[i];
    }
#pragma unroll
    for (int os = 32; os > 0; os >>= 1) sum += __shfl_xor(sum, os);
    float inv = 1.0f / sum;
    f16x8 p;
#pragma unroll
    for (int i = 0; i < 8; ++i) p[i] = (_Float16)(e[i] * inv);
    *(f16x8*)(h0 + o) = p;
}

// ============ A-only-LDS GEMM: BM=256 x BN=128, 8 waves, 2-buf ring, B from L2 ============
// Rationale (r7-r11 data): per-iter wall is stall-dominated and work-independent,
// so time ~ NTI. B operands here (WaT 4.2MB, WcT 4.2MB) are L2/L3-resident ->
// read B fragments DIRECTLY from global (plain loads; compiler inserts vmcnt),
// freeing LDS so the A ring can hold BKI=64 (3-term) / BKI=128 (1-term):
// NTI = 16 instead of 32. MFMA order per accumulator identical to r11 (bitwise
// same output). A staged via gl_lds with the proven swizzle (src pre-swizzled,
// dest linear, swizzled ds_read). One vmcnt(0)+barrier per iter (A-stage for
// t+1 issued at iter start -> latency fully covered by the iter body).
// ACON: A = [Ahi | A2] along k (both lda), switch at k=HH (BKI-aligned).
// EPI: 1 = bf16 split store; 2 = fast-tanh(x+bias) fp32; 3 = f16 store
template <int PREC, int TERMS, int EPI, int ACON>
__global__ __launch_bounds__(512, 2)
void gemm_q(const u16* __restrict__ Ahi, const u16* __restrict__ Alo,
            const u16* __restrict__ A2,
            const u16* __restrict__ Bhi, const u16* __restrict__ Blo,
            float* __restrict__ C, u16* __restrict__ Chi, u16* __restrict__ Clo,
            const float* __restrict__ bias,
            int N, int K, int lda, int ldb) {
    constexpr int SUBS = (TERMS == 3) ? 2 : 4;  // BKI = 64 / 128
    constexpr int BKI = 32 * SUBS;
    constexpr int ASZ = 8192;                   // u16 per 256x32 A array
    constexpr int NARR = (TERMS == 3) ? 2 : 1;  // Ah [, Al]
    constexpr int BUFU = SUBS * NARR * ASZ;     // 32768 u16 = 64KB both ways

    __shared__ u16 lds[2 * BUFU];  // 128 KB -> 1 block/CU

    // XCD-chunked swizzle: 256 blocks, 8 chunks of 32
    int id = blockIdx.x;
    int ns = ((id & 7) << 5) | (id >> 3);
    int by = ns >> 3;
    int bx = ns & 7;

    int tid = threadIdx.x;
    int lane = tid & 63;
    int wave = tid >> 6;
    int wm = (wave >> 1) * 64;
    int wn = (wave & 1) * 64;
    int fr = lane & 15;
    int kq = lane >> 4;
    int m0 = by * 256;
    int n0 = bx * 128;

    f32x4 acc[4][4];
#pragma unroll
    for (int i = 0; i < 4; ++i)
#pragma unroll
        for (int j = 0; j < 4; ++j) acc[i][j] = (f32x4){0.f, 0.f, 0.f, 0.f};

    // stage one 256x32 A array via gl_lds (global src pre-swizzled, dest linear)
    auto stage_arr = [&](int dst, const u16* g, int k0) {
#pragma unroll
        for (int h = 0; h < 2; ++h) {
            int vt = tid + h * 512;
            int row = vt >> 2;
            int ls = (vt & 3) ^ ((row >> 1) & 3);
            const u16* gp = g + (long)(m0 + row) * lda + (k0 + 8 * ls);
            u16* lp = lds + dst + ((tid & ~63) + h * 512) * 8;  // wave-uniform
            gl16(gp, lp);
        }
    };
    // stage A for k-iter t: 8 gl16/thread (both TERMS variants)
    auto stage = [&](int bi, int t) {
#pragma unroll
        for (int s = 0; s < SUBS; ++s) {
            int ks = t * BKI + s * 32;
            int sb = bi * BUFU + s * NARR * ASZ;
            if (ACON) {
                if (ks < HH)
                    stage_arr(sb, Ahi, ks);
                else
                    stage_arr(sb, A2, ks - HH);
            } else {
                stage_arr(sb, Ahi, ks);
                if (TERMS == 3) stage_arr(sb + ASZ, Alo, ks);
            }
        }
    };

    const int NTI = K / BKI;
    stage(0, 0);
    asm volatile("s_waitcnt vmcnt(0)" ::: "memory");
    __builtin_amdgcn_sched_barrier(0);
    __builtin_amdgcn_s_barrier();
    __builtin_amdgcn_sched_barrier(0);

    using FT = typename FragT<PREC>::T;
    for (int t = 0; t < NTI; ++t) {
        if (t + 1 < NTI) stage((t + 1) & 1, t + 1);  // A prefetch into other buf

        const u16* Lb = lds + (t & 1) * BUFU;
#pragma unroll
        for (int s = 0; s < SUBS; ++s) {
            const u16* Ls = Lb + s * NARR * ASZ;
            int ks = t * BKI + s * 32;
            FT afh[4], afl[4], bfh[4], bfl[4];
#pragma unroll
            for (int i = 0; i < 4; ++i) {
                int ra = wm + i * 16 + fr;
                int oa = ra * 32 + ((kq ^ ((ra >> 1) & 3)) << 3);
                afh[i] = *(const FT*)(Ls + oa);
                if (TERMS == 3) afl[i] = *(const FT*)(Ls + ASZ + oa);
            }
            // B fragments straight from global (L2-resident; plain loads ->
            // compiler-managed vmcnt). Same logical values the LDS round-trip
            // delivered before.
#pragma unroll
            for (int j = 0; j < 4; ++j) {
                long rb = n0 + wn + j * 16 + fr;
                bfh[j] = *(const FT*)(Bhi + rb * ldb + ks + kq * 8);
                if (TERMS == 3) bfl[j] = *(const FT*)(Blo + rb * ldb + ks + kq * 8);
            }
            __builtin_amdgcn_s_setprio(1);
#pragma unroll
            for (int i = 0; i < 4; ++i)
#pragma unroll
                for (int j = 0; j < 4; ++j) {
                    acc[i][j] = mfma16(afh[i], bfh[j], acc[i][j]);
                    if (TERMS == 3) {
                        acc[i][j] = mfma16(afl[i], bfh[j], acc[i][j]);
                        acc[i][j] = mfma16(afh[i], bfl[j], acc[i][j]);
                    }
                }
            __builtin_amdgcn_s_setprio(0);
        }
        if (t < NTI - 1) {
            __builtin_amdgcn_sched_barrier(0);
            asm volatile("s_waitcnt vmcnt(0)" ::: "memory");  // A-stage landed (issued at iter start)
            __builtin_amdgcn_sched_barrier(0);
            __builtin_amdgcn_s_barrier();
            __builtin_amdgcn_sched_barrier(0);
        }
    }

    int fq = (lane >> 4) * 4;
#pragma unroll
    for (int i = 0; i < 4; ++i)
#pragma unroll
        for (int j = 0; j < 4; ++j)
#pragma unroll
            for (int g = 0; g < 4; ++g) {
                int row = m0 + wm + i * 16 + fq + g;
                int col = n0 + wn + j * 16 + fr;
                long idx = (long)row * N + col;
                float v = acc[i][j][g];
                if constexpr (EPI == 1) {
                    u16 h2, l2;
                    split_bf(v, h2, l2);
                    Chi[idx] = h2;
                    Clo[idx] = l2;
                } else if constexpr (EPI == 2) {
                    float x = v + bias[col];
                    float t2 = __expf(2.f * x);
                    C[idx] = 1.f - 2.f * __builtin_amdgcn_rcpf(t2 + 1.f);
                } else {
                    Chi[idx] = __builtin_bit_cast(u16, (_Float16)v);
                }
            }
}

// ============ 2-phase GEMM (r6-proven) — G2 (reg-staged fp32 ht) and G3 ============
template <int PREC, int ASRC, int EPI, int TERMS, int KSPLIT, bool SWZ>
__global__ __launch_bounds__(256, 2)
void gemm_u(const u16* __restrict__ Ahi, const u16* __restrict__ Alo,
            const float* __restrict__ Af,
            const u16* __restrict__ Bhi, const u16* __restrict__ Blo,
            float* __restrict__ C, u16* __restrict__ Chi, u16* __restrict__ Clo,
            const float* __restrict__ bias,
            int M, int N, int K, int lda, int ldb,
            long sA, long sB, long sC, long sKh) {
    int bx, by, bz;
    if (SWZ) {
        int id = blockIdx.x;
        int ns = ((id & 7) << 6) | (id >> 3);
        bx = ns & 7;
        by = ns >> 3;
        bz = 0;
    } else {
        bx = blockIdx.x;
        by = blockIdx.y;
        bz = blockIdx.z;
    }
    int kh = 0;
    if (KSPLIT == 2) {
        kh = bz & 1;
        bz >>= 1;
    }
    if (ASRC == 0) {
        Ahi += (long)bz * sA + (long)kh * K;
        if (TERMS == 3) Alo += (long)bz * sA + (long)kh * K;
    } else if (ASRC == 1) {
        Af += (long)bz * sA + (long)kh * K;
    }
    Bhi += (long)bz * sB + (long)kh * K;
    if (TERMS == 3) Blo += (long)bz * sB + (long)kh * K;

    int n0 = bx * 128;
    int m0 = by * 128;

    constexpr int NARR = (TERMS == 3) ? 4 : 2;
    constexpr int AH = 0, AL = 1;
    constexpr int BH = (TERMS == 3) ? 2 : 1;
    constexpr int BL = 3;
    __shared__ u16 lds[2][NARR * 4096];

    int tid = threadIdx.x;
    int lane = tid & 63;
    int wave = tid >> 6;
    int wm = (wave >> 1) * 64;
    int wn = (wave & 1) * 64;
    int fr = lane & 15;
    int kq = lane >> 4;

    f32x4 acc[4][4];
#pragma unroll
    for (int i = 0; i < 4; ++i)
#pragma unroll
        for (int j = 0; j < 4; ++j) acc[i][j] = (f32x4){0.f, 0.f, 0.f, 0.f};

    auto stage_gl = [&](int bufi, int arr, const u16* g, int r0, int ldg, int k0) {
#pragma unroll
        for (int h = 0; h < 2; ++h) {
            int vt = tid + h * 256;
            int row = vt >> 2;
            int ls = (vt & 3) ^ ((row >> 1) & 3);
            const u16* gp = g + (long)(r0 + row) * ldg + (k0 + 8 * ls);
            u16* lp = &lds[bufi][arr * 4096 + (vt >> 6) * 512];
            gl16(gp, lp);
        }
    };

    auto stage_a_f32 = [&](int bufi, const float* g, int ldg, int kk) {
        int r = tid >> 1;
        int hf = (tid & 1) * 16;
        const float* p = g + (long)(m0 + r) * ldg + kk + hf;
        float4 a0 = *(const float4*)(p + 0);
        float4 a1 = *(const float4*)(p + 4);
        float4 a2 = *(const float4*)(p + 8);
        float4 a3 = *(const float4*)(p + 12);
        float fv[16] = {a0.x, a0.y, a0.z, a0.w, a1.x, a1.y, a1.z, a1.w,
                        a2.x, a2.y, a2.z, a2.w, a3.x, a3.y, a3.z, a3.w};
        u16 hb[16], lb[16];
#pragma unroll
        for (int i = 0; i < 16; ++i) {
            if constexpr (PREC == 0)
                split_bf(fv[i], hb[i], lb[i]);
            else
                hb[i] = __builtin_bit_cast(u16, (_Float16)fv[i]);
        }
        int sw = (r >> 1) & 3;
        int ls0 = hf >> 3;
        u32x4 h0 = {(u32)hb[0] | ((u32)hb[1] << 16), (u32)hb[2] | ((u32)hb[3] << 16),
                    (u32)hb[4] | ((u32)hb[5] << 16), (u32)hb[6] | ((u32)hb[7] << 16)};
        u32x4 h1 = {(u32)hb[8] | ((u32)hb[9] << 16), (u32)hb[10] | ((u32)hb[11] << 16),
                    (u32)hb[12] | ((u32)hb[13] << 16), (u32)hb[14] | ((u32)hb[15] << 16)};
        u16* ah = &lds[bufi][AH * 4096 + r * 32];
        *(u32x4*)(ah + (((ls0 + 0) ^ sw) << 3)) = h0;
        *(u32x4*)(ah + (((ls0 + 1) ^ sw) << 3)) = h1;
        if constexpr (TERMS == 3) {
            u32x4 l0 = {(u32)lb[0] | ((u32)lb[1] << 16), (u32)lb[2] | ((u32)lb[3] << 16),
                        (u32)lb[4] | ((u32)lb[5] << 16), (u32)lb[6] | ((u32)lb[7] << 16)};
            u32x4 l1 = {(u32)lb[8] | ((u32)lb[9] << 16), (u32)lb[10] | ((u32)lb[11] << 16),
                        (u32)lb[12] | ((u32)lb[13] << 16), (u32)lb[14] | ((u32)lb[15] << 16)};
            u16* al = &lds[bufi][AL * 4096 + r * 32];
            *(u32x4*)(al + (((ls0 + 0) ^ sw) << 3)) = l0;
            *(u32x4*)(al + (((ls0 + 1) ^ sw) << 3)) = l1;
        }
    };

    auto stage = [&](int bufi, int t) {
        int k0 = t * 32;
        stage_gl(bufi, BH, Bhi, n0, ldb, k0);
        if (TERMS == 3) stage_gl(bufi, BL, Blo, n0, ldb, k0);
        if (ASRC == 0) {
            stage_gl(bufi, AH, Ahi, m0, lda, k0);
            if (TERMS == 3) stage_gl(bufi, AL, Alo, m0, lda, k0);
        } else {
            stage_a_f32(bufi, Af, lda, k0);
        }
    };

    const int NT = K / 32;
    stage(0, 0);
    __syncthreads();
    int cur = 0;
    using FT = typename FragT<PREC>::T;
    for (int t = 0; t < NT; ++t) {
        if (t + 1 < NT) stage(cur ^ 1, t + 1);

        const u16* L = lds[cur];
        FT afh[4], afl[4], bfh[4], bfl[4];
#pragma unroll
        for (int i = 0; i < 4; ++i) {
            int ra = wm + i * 16 + fr;
            int rb = wn + i * 16 + fr;
            int oa = ra * 32 + ((kq ^ ((ra >> 1) & 3)) << 3);
            int ob = rb * 32 + ((kq ^ ((rb >> 1) & 3)) << 3);
            afh[i] = *(const FT*)(L + AH * 4096 + oa);
            bfh[i] = *(const FT*)(L + BH * 4096 + ob);
            if (TERMS == 3) {
                afl[i] = *(const FT*)(L + AL * 4096 + oa);
                bfl[i] = *(const FT*)(L + BL * 4096 + ob);
            }
        }
#pragma unroll
        for (int i = 0; i < 4; ++i)
#pragma unroll
            for (int j = 0; j < 4; ++j) {
                acc[i][j] = mfma16(afh[i], bfh[j], acc[i][j]);
                if (TERMS == 3) {
                    acc[i][j] = mfma16(afl[i], bfh[j], acc[i][j]);
                    acc[i][j] = mfma16(afh[i], bfl[j], acc[i][j]);
                }
            }
        __syncthreads();
        cur ^= 1;
    }

    long obase = (long)bz * sC + (long)kh * sKh;
    int fq = (lane >> 4) * 4;
#pragma unroll
    for (int i = 0; i < 4; ++i)
#pragma unroll
        for (int j = 0; j < 4; ++j)
#pragma unroll
            for (int g = 0; g < 4; ++g) {
                int row = m0 + wm + i * 16 + fq + g;
                int col = n0 + wn + j * 16 + fr;
                long idx = obase + (long)row * N + col;
                float v = acc[i][j][g];
                if constexpr (EPI == 1) {
                    u16 h2, l2;
                    split_bf(v, h2, l2);
                    Chi[idx] = h2;
                    Clo[idx] = l2;
                } else if constexpr (EPI == 2) {
                    float x = v + bias[col];
                    float t2 = __expf(2.f * x);
                    C[idx] = 1.f - 2.f * __builtin_amdgcn_rcpf(t2 + 1.f);
                } else {
                    Chi[idx] = __builtin_bit_cast(u16, (_Float16)v);
                }
            }
}

extern "C" void kernel_launch(void* const* d_in, const int* in_sizes, int n_in,
                              void* d_out, int out_size, void* d_ws, size_t ws_size,
                              hipStream_t stream) {
    const float* ht = (const float*)d_in[0];
    const float* hs = (const float*)d_in[1];
    const int* source = (const int*)d_in[2];
    const float* Wa = (const float*)d_in[3];
    const float* Wc = (const float*)d_in[4];
    const float* bias = (const float*)d_in[5];
    float* out = (float*)d_out;

    char* w = (char*)d_ws;
    size_t off = 0;
    auto alloc = [&](size_t bytes) -> void* {
        void* p = w + off;
        off += (bytes + 255) & ~(size_t)255;
        return p;
    };
    int* lens = (int*)alloc(256);
    u16* keysHi = (u16*)alloc((size_t)BB * TS * HH * 2);  // 16.78 MB (bf16)
    u16* keysLo = (u16*)alloc((size_t)BB * TS * HH * 2);
    u16* hsRHi = (u16*)alloc((size_t)BB * TS * HH * 2);   // dead after G1
    u16* hsRLo = (u16*)alloc((size_t)BB * TS * HH * 2);
    u16* hsTHi = (u16*)alloc((size_t)BB * HH * TS * 2);   // f16; dead after G3
    u16* WaTHi = (u16*)alloc((size_t)HH * HH * 2);
    u16* WaTLo = (u16*)alloc((size_t)HH * HH * 2);
    // total ~88.1 MB (proven since r2). Overlays (identical to r11):
    u16* scoreH0 = hsRHi;
    u16* scoreH1 = hsRHi + (size_t)BB * TT * TS;
    u16* scoreL0 = hsRLo;
    u16* scoreL1 = hsRLo + (size_t)BB * TT * TS;
    u16* cHi = keysHi;
    u16* WcTHi = scoreL0;
    u16* htF = hsTHi;
    u16* prob = scoreH0;

    // prep1: hs_prep (8192) | WaT transpose (1024) | lens (16) in one launch
    prep1_kernel<<<8192 + 1024 + 16, 256, 0, stream>>>(
        hs, hsRHi, hsRLo, hsTHi, Wa, WaTHi, WaTLo, source, lens);

    // G1: keys = hs @ Wa  (bf16 3-term, A-only-LDS gemm_q, BKI=64 -> NTI=16;
    //     B = WaT hi/lo 4.2MB L2-resident, read direct)
    gemm_q<0, 3, 1, 0><<<256, 512, 0, stream>>>(
        hsRHi, hsRLo, nullptr, WaTHi, WaTLo,
        nullptr, keysHi, keysLo, nullptr,
        HH, HH, HH, HH);

    // G2: score[b] = ht[b] @ keys[b]^T  (bf16 3-term, 2-phase gemm_u, split-K=2)
    gemm_u<0, 1, 1, 3, 2, false><<<dim3(TS / 128, TT / 128, 2 * BB), 256, 0, stream>>>(
        nullptr, nullptr, ht, keysHi, keysLo,
        nullptr, scoreH0, scoreL0, nullptr,
        TT, TS, HH / 2, HH, HH,
        (long)TT * HH, (long)TS * HH, (long)TT * TS, (long)BB * TT * TS);

    softmax_mask_kernel<<<BB * TT, 64, 0, stream>>>(scoreH0, scoreL0, scoreH1, scoreL1, lens);

    // G3: c[b] = prob[b] @ hs[b]  (f16 1-term, 2-phase gemm_u)
    gemm_u<1, 0, 3, 1, 1, false><<<dim3(HH / 128, TT / 128, BB), 256, 0, stream>>>(
        prob, nullptr, nullptr, hsTHi, nullptr,
        nullptr, cHi, nullptr, nullptr,
        TT, HH, TS, TS, TS,
        (long)TT * TS, (long)HH * TS, (long)TT * HH, 0);

    // prep2: htF f16 (4096) | WcT f16 transpose (2048) in one launch
    prep2_kernel<<<4096 + 2048, 256, 0, stream>>>(ht, htF, Wc, WcTHi);

    // G4: out = tanh(concat(c, ht) @ Wc + b)  (f16 1-term, gemm_q ACON,
    //     BKI=128 -> NTI=16; B = WcT f16 4.2MB L2-resident, read direct)
    gemm_q<1, 1, 2, 1><<<256, 512, 0, stream>>>(
        cHi, nullptr, htF, WcTHi, nullptr,
        out, nullptr, nullptr, bias,
        OO, 2 * HH, HH, 2 * HH);
}

// Round 13
// 190.204 us; speedup vs baseline: 1.4043x; 1.4043x over previous
//
#include <hip/hip_runtime.h>
#include <math.h>

typedef unsigned short u16;
typedef unsigned int u32;

using f32x4 = __attribute__((ext_vector_type(4))) float;
using s16x8 = __attribute__((ext_vector_type(8))) short;
using f16x8 = __attribute__((ext_vector_type(8))) _Float16;
using u32x4 = __attribute__((ext_vector_type(4))) u32;

#define DEVI static __device__ __forceinline__

// ---- problem constants ----
#define BB 16
#define TT 512
#define TS 512
#define HH 1024
#define OO 1024

// bf16 split: x = hi + lo + eps, |eps| <= 2^-16 |x|
DEVI void split_bf(float x, u16& hb, u16& lb) {
    u32 xb = __float_as_uint(x);
    float hf = __uint_as_float(xb & 0xffff0000u);
    hb = (u16)(xb >> 16);
    lb = (u16)(__float_as_uint(x - hf) >> 16);
}

DEVI float ub(u16 h) { return __uint_as_float((u32)h << 16); }

template <int PREC> struct FragT;
template <> struct FragT<0> { using T = s16x8; };
template <> struct FragT<1> { using T = f16x8; };

DEVI f32x4 mfma16(s16x8 a, s16x8 b, f32x4 c) {
    return __builtin_amdgcn_mfma_f32_16x16x32_bf16(a, b, c, 0, 0, 0);
}
DEVI f32x4 mfma16(f16x8 a, f16x8 b, f32x4 c) {
    return __builtin_amdgcn_mfma_f32_16x16x32_f16(a, b, c, 0, 0, 0);
}

// async global->LDS, 16B/lane; LDS dest wave-uniform base + lane*16
DEVI void gl16(const void* g, void* l) {
    __builtin_amdgcn_global_load_lds(
        (__attribute__((address_space(1))) const void*)g,
        (__attribute__((address_space(3))) void*)l, 16, 0, 0);
}

// ============ fused prep 1: hs_prep (8192 blocks) | WaT transpose (1024) | lens (16) ============
__global__ void prep1_kernel(const float* __restrict__ hs,
                             u16* __restrict__ rhi, u16* __restrict__ rlo,
                             u16* __restrict__ thi,
                             const float* __restrict__ Wa,
                             u16* __restrict__ whi, u16* __restrict__ wlo,
                             const int* __restrict__ src, int* __restrict__ lens) {
    __shared__ float tile[32][33];
    __shared__ int part[4];
    int id = blockIdx.x;
    int tid = threadIdx.x;
    int tx = tid & 31, ty = tid >> 5;  // 32 x 8
    if (id < 8192) {
        int bx = id & 31, by = (id >> 5) & 15, bz = id >> 9;
        long boff = (long)bz * TS * HH;
        const float* s = hs + boff;
        u16* rh = rhi + boff;
        u16* rl = rlo + boff;
        u16* th = thi + boff;
        int c0 = bx * 32, r0 = by * 32;
#pragma unroll
        for (int i = 0; i < 32; i += 8) {
            long o = (long)(r0 + ty + i) * HH + (c0 + tx);
            float v = s[o];
            tile[ty + i][tx] = v;
            u16 hb, lb;
            split_bf(v, hb, lb);
            rh[o] = hb;
            rl[o] = lb;
        }
        __syncthreads();
#pragma unroll
        for (int i = 0; i < 32; i += 8) {
            long o = (long)(c0 + ty + i) * TS + (r0 + tx);
            th[o] = __builtin_bit_cast(u16, (_Float16)tile[tx][ty + i]);
        }
    } else if (id < 8192 + 1024) {
        int id2 = id - 8192;
        int bx = id2 & 31, by = id2 >> 5;
        int c0 = bx * 32, r0 = by * 32;
#pragma unroll
        for (int i = 0; i < 32; i += 8)
            tile[ty + i][tx] = Wa[(long)(r0 + ty + i) * HH + (c0 + tx)];
        __syncthreads();
#pragma unroll
        for (int i = 0; i < 32; i += 8) {
            u16 hb, lb;
            split_bf(tile[tx][ty + i], hb, lb);
            long o = (long)(c0 + ty + i) * HH + (r0 + tx);
            whi[o] = hb;
            wlo[o] = lb;
        }
    } else {
        int b = id - (8192 + 1024);
        int v0 = (src[b * TS + tid] != 0) ? 1 : 0;
        int v1 = (src[b * TS + 256 + tid] != 0) ? 1 : 0;
        unsigned long long m0 = __ballot(v0);
        unsigned long long m1 = __ballot(v1);
        if ((tid & 63) == 0) part[tid >> 6] = __popcll(m0) + __popcll(m1);
        __syncthreads();
        if (tid == 0) lens[b] = part[0] + part[1] + part[2] + part[3];
    }
}

// ============ fused prep 2: htF f16 (4096 blocks) | WcT f16 transpose (2048) ============
__global__ void prep2_kernel(const float* __restrict__ ht, u16* __restrict__ htF,
                             const float* __restrict__ Wc, u16* __restrict__ wcthi) {
    __shared__ float tile[32][33];
    int id = blockIdx.x;
    int tid = threadIdx.x;
    if (id < 4096) {
        long i = ((long)id * 256 + tid) * 8;
        float4 v0 = *(const float4*)(ht + i);
        float4 v1 = *(const float4*)(ht + i + 4);
        float fv[8] = {v0.x, v0.y, v0.z, v0.w, v1.x, v1.y, v1.z, v1.w};
        f16x8 o;
#pragma unroll
        for (int j = 0; j < 8; ++j) o[j] = (_Float16)fv[j];
        *(f16x8*)(htF + i) = o;
    } else {
        int id2 = id - 4096;
        int bx = id2 & 31, by = id2 >> 5;
        int tx = tid & 31, ty = tid >> 5;
        int c0 = bx * 32, r0 = by * 32;
#pragma unroll
        for (int i = 0; i < 32; i += 8)
            tile[ty + i][tx] = Wc[(long)(r0 + ty + i) * OO + (c0 + tx)];
        __syncthreads();
#pragma unroll
        for (int i = 0; i < 32; i += 8) {
            long o = (long)(c0 + ty + i) * (2 * HH) + (r0 + tx);
            wcthi[o] = __builtin_bit_cast(u16, (_Float16)tile[tx][ty + i]);
        }
    }
}

// masked softmax: full score = (h0+l0)+(h1+l1) bf16 parts, 1 wave/row.
// rowmax over FULL row, exp, prefix mask, normalize; writes f16 prob into h0.
__global__ void softmax_mask_kernel(u16* __restrict__ h0, u16* __restrict__ l0,
                                    const u16* __restrict__ h1, const u16* __restrict__ l1,
                                    const int* __restrict__ lens) {
    long row = blockIdx.x;
    int len = lens[blockIdx.x >> 9];
    int lane = threadIdx.x;
    long o = row * TS + 8 * lane;
    s16x8 vh0 = *(const s16x8*)(h0 + o);
    s16x8 vl0 = *(const s16x8*)(l0 + o);
    s16x8 vh1 = *(const s16x8*)(h1 + o);
    s16x8 vl1 = *(const s16x8*)(l1 + o);
    float f[8];
#pragma unroll
    for (int i = 0; i < 8; ++i)
        f[i] = (ub((u16)vh0[i]) + ub((u16)vl0[i])) + (ub((u16)vh1[i]) + ub((u16)vl1[i]));
    float m = f[0];
#pragma unroll
    for (int i = 1; i < 8; ++i) m = fmaxf(m, f[i]);
#pragma unroll
    for (int os = 32; os > 0; os >>= 1) m = fmaxf(m, __shfl_xor(m, os));
    float e[8];
    float sum = 0.f;
#pragma unroll
    for (int i = 0; i < 8; ++i) {
        e[i] = (8 * lane + i < len) ? expf(f[i] - m) : 0.f;
        sum += e[i];
    }
#pragma unroll
    for (int os = 32; os > 0; os >>= 1) sum += __shfl_xor(sum, os);
    float inv = 1.0f / sum;
    f16x8 p;
#pragma unroll
    for (int i = 0; i < 8; ++i) p[i] = (_Float16)(e[i] * inv);
    *(f16x8*)(h0 + o) = p;
}

// ============ deep-pipelined GEMM (r8/r11-proven): BM=256 x BN=128, 8 waves, 3-buf ring ============
// Monolithic per-iter schedule. All operands pre-split u16, pure global_load_lds
// (r12 lesson: B must stay on the gl_lds path — plain B loads share the vmcnt
// counter with the A prefetch and force full drains every sub-step, -78%).
// TERMS=3 (bf16, BK=32) or TERMS=1 (f16, BK=64 = 2 subs). Per iter: issue
// stage(t+2), ds_read frags(buf t), MFMA (setprio), s_waitcnt vmcnt(6)
// [never 0 mid-loop], s_barrier.
// LDS swizzle off_u16 = row*32 + 8*(slot ^ ((row>>1)&3)): applied on global src
// for gl_lds (dest linear, rule #21) and on ds_read addrs.
// ACON: A = [Ahi | A2] along k (both pre-split, lda), switch at k=HH.
// EPI: 1 = bf16 split store; 2 = fast-tanh(x+bias) fp32; 3 = f16 store
template <int PREC, int TERMS, int EPI, int ACON, int KSPLIT, int SWZ>
__global__ __launch_bounds__(512, 2)
void gemm_p(const u16* __restrict__ Ahi, const u16* __restrict__ Alo,
            const u16* __restrict__ A2,
            const u16* __restrict__ Bhi, const u16* __restrict__ Blo,
            float* __restrict__ C, u16* __restrict__ Chi, u16* __restrict__ Clo,
            const float* __restrict__ bias,
            int N, int K, int lda, int ldb,
            long sA, long sB, long sC, long sKh) {
    constexpr int SUBS = (TERMS == 3) ? 1 : 2;
    constexpr int BKI = 32 * SUBS;
    constexpr int SUBU = (TERMS == 3) ? 24576 : 12288;
    constexpr int BUFU = 24576;  // 48 KB per ring buffer
    constexpr int AHo = 0;
    constexpr int ALof = 8192;
    constexpr int BHo = (TERMS == 3) ? 16384 : 8192;
    constexpr int BLof = 20480;

    __shared__ u16 lds[3 * BUFU];  // 144 KB -> 1 block/CU

    int bx, by, bz = 0;
    if (SWZ) {
        int id = blockIdx.x;  // 256 blocks, 8 XCD chunks of 32
        int ns = ((id & 7) << 5) | (id >> 3);
        by = ns >> 3;
        bx = ns & 7;
    } else {
        bx = blockIdx.x;
        by = blockIdx.y;
        bz = blockIdx.z;
    }
    int kh = 0;
    if (KSPLIT == 2) {
        kh = bz & 1;
        bz >>= 1;
    }
    if (!ACON) {
        Ahi += (long)bz * sA + (long)kh * K;
        if (TERMS == 3) Alo += (long)bz * sA + (long)kh * K;
    }
    Bhi += (long)bz * sB + (long)kh * K;
    if (TERMS == 3) Blo += (long)bz * sB + (long)kh * K;

    int tid = threadIdx.x;
    int lane = tid & 63;
    int wave = tid >> 6;
    int wm = (wave >> 1) * 64;
    int wn = (wave & 1) * 64;
    int fr = lane & 15;
    int kq = lane >> 4;
    int m0 = by * 256;
    int n0 = bx * 128;

    f32x4 acc[4][4];
#pragma unroll
    for (int i = 0; i < 4; ++i)
#pragma unroll
        for (int j = 0; j < 4; ++j) acc[i][j] = (f32x4){0.f, 0.f, 0.f, 0.f};

    auto stage_arr = [&](int dst, const u16* g, int r0, int ldg, int k0, int cnt) {
#pragma unroll
        for (int h = 0; h < cnt; ++h) {
            int vt = tid + h * 512;
            int row = vt >> 2;
            int ls = (vt & 3) ^ ((row >> 1) & 3);
            const u16* gp = g + (long)(r0 + row) * ldg + (k0 + 8 * ls);
            u16* lp = lds + dst + ((tid & ~63) + h * 512) * 8;  // wave-uniform
            gl16(gp, lp);
        }
    };
    // exactly 6 gl16 per thread per stage() for both TERMS variants
    auto stage = [&](int bi, int t) {
#pragma unroll
        for (int s = 0; s < SUBS; ++s) {
            int ks = t * BKI + s * 32;
            int sb = bi * BUFU + s * ((TERMS == 3) ? 0 : SUBU);
            if (ACON) {
                if (ks < HH)
                    stage_arr(sb + AHo, Ahi, m0, lda, ks, 2);
                else
                    stage_arr(sb + AHo, A2, m0, lda, ks - HH, 2);
            } else {
                stage_arr(sb + AHo, Ahi, m0, lda, ks, 2);
                if (TERMS == 3) stage_arr(sb + ALof, Alo, m0, lda, ks, 2);
            }
            stage_arr(sb + BHo, Bhi, n0, ldb, ks, 1);
            if (TERMS == 3) stage_arr(sb + BLof, Blo, n0, ldb, ks, 1);
        }
    };

    const int NTI = K / BKI;
    stage(0, 0);
    stage(1, 1);
    stage(2, 2);
    asm volatile("s_waitcnt vmcnt(12)" ::: "memory");  // buf0 landed; 1,2 in flight
    __builtin_amdgcn_sched_barrier(0);
    __builtin_amdgcn_s_barrier();
    __builtin_amdgcn_sched_barrier(0);

    using FT = typename FragT<PREC>::T;
    for (int t = 0; t < NTI; ++t) {
        if (t >= 1 && t + 2 < NTI) stage((t + 2) % 3, t + 2);

        const u16* Lb = lds + (t % 3) * BUFU;
#pragma unroll
        for (int s = 0; s < SUBS; ++s) {
            const u16* Ls = Lb + s * SUBU;
            FT afh[4], afl[4], bfh[4], bfl[4];
#pragma unroll
            for (int i = 0; i < 4; ++i) {
                int ra = wm + i * 16 + fr;
                int rb = wn + i * 16 + fr;
                int oa = ra * 32 + ((kq ^ ((ra >> 1) & 3)) << 3);
                int ob = rb * 32 + ((kq ^ ((rb >> 1) & 3)) << 3);
                afh[i] = *(const FT*)(Ls + AHo + oa);
                bfh[i] = *(const FT*)(Ls + BHo + ob);
                if (TERMS == 3) {
                    afl[i] = *(const FT*)(Ls + ALof + oa);
                    bfl[i] = *(const FT*)(Ls + BLof + ob);
                }
            }
            __builtin_amdgcn_s_setprio(1);
#pragma unroll
            for (int i = 0; i < 4; ++i)
#pragma unroll
                for (int j = 0; j < 4; ++j) {
                    acc[i][j] = mfma16(afh[i], bfh[j], acc[i][j]);
                    if (TERMS == 3) {
                        acc[i][j] = mfma16(afl[i], bfh[j], acc[i][j]);
                        acc[i][j] = mfma16(afh[i], bfl[j], acc[i][j]);
                    }
                }
            __builtin_amdgcn_s_setprio(0);
        }
        if (t < NTI - 1) {
            __builtin_amdgcn_sched_barrier(0);
            if (t + 2 < NTI)
                asm volatile("s_waitcnt vmcnt(6)" ::: "memory");  // newest stage stays in flight
            else
                asm volatile("s_waitcnt vmcnt(0)" ::: "memory");  // epilogue drain
            __builtin_amdgcn_sched_barrier(0);
            __builtin_amdgcn_s_barrier();
            __builtin_amdgcn_sched_barrier(0);
        }
    }

    long obase = (long)bz * sC + (long)kh * sKh;
    int fq = (lane >> 4) * 4;
#pragma unroll
    for (int i = 0; i < 4; ++i)
#pragma unroll
        for (int j = 0; j < 4; ++j)
#pragma unroll
            for (int g = 0; g < 4; ++g) {
                int row = m0 + wm + i * 16 + fq + g;
                int col = n0 + wn + j * 16 + fr;
                long idx = obase + (long)row * N + col;
                float v = acc[i][j][g];
                if constexpr (EPI == 1) {
                    u16 h2, l2;
                    split_bf(v, h2, l2);
                    Chi[idx] = h2;
                    Clo[idx] = l2;
                } else if constexpr (EPI == 2) {
                    float x = v + bias[col];
                    float t2 = __expf(2.f * x);
                    C[idx] = 1.f - 2.f * __builtin_amdgcn_rcpf(t2 + 1.f);
                } else {
                    Chi[idx] = __builtin_bit_cast(u16, (_Float16)v);
                }
            }
}

// ============ 2-phase GEMM (r6-proven) — G2 (reg-staged fp32 ht) and G3 ============
template <int PREC, int ASRC, int EPI, int TERMS, int KSPLIT, bool SWZ>
__global__ __launch_bounds__(256, 2)
void gemm_u(const u16* __restrict__ Ahi, const u16* __restrict__ Alo,
            const float* __restrict__ Af,
            const u16* __restrict__ Bhi, const u16* __restrict__ Blo,
            float* __restrict__ C, u16* __restrict__ Chi, u16* __restrict__ Clo,
            const float* __restrict__ bias,
            int M, int N, int K, int lda, int ldb,
            long sA, long sB, long sC, long sKh) {
    int bx, by, bz;
    if (SWZ) {
        int id = blockIdx.x;
        int ns = ((id & 7) << 6) | (id >> 3);
        bx = ns & 7;
        by = ns >> 3;
        bz = 0;
    } else {
        bx = blockIdx.x;
        by = blockIdx.y;
        bz = blockIdx.z;
    }
    int kh = 0;
    if (KSPLIT == 2) {
        kh = bz & 1;
        bz >>= 1;
    }
    if (ASRC == 0) {
        Ahi += (long)bz * sA + (long)kh * K;
        if (TERMS == 3) Alo += (long)bz * sA + (long)kh * K;
    } else if (ASRC == 1) {
        Af += (long)bz * sA + (long)kh * K;
    }
    Bhi += (long)bz * sB + (long)kh * K;
    if (TERMS == 3) Blo += (long)bz * sB + (long)kh * K;

    int n0 = bx * 128;
    int m0 = by * 128;

    constexpr int NARR = (TERMS == 3) ? 4 : 2;
    constexpr int AH = 0, AL = 1;
    constexpr int BH = (TERMS == 3) ? 2 : 1;
    constexpr int BL = 3;
    __shared__ u16 lds[2][NARR * 4096];

    int tid = threadIdx.x;
    int lane = tid & 63;
    int wave = tid >> 6;
    int wm = (wave >> 1) * 64;
    int wn = (wave & 1) * 64;
    int fr = lane & 15;
    int kq = lane >> 4;

    f32x4 acc[4][4];
#pragma unroll
    for (int i = 0; i < 4; ++i)
#pragma unroll
        for (int j = 0; j < 4; ++j) acc[i][j] = (f32x4){0.f, 0.f, 0.f, 0.f};

    auto stage_gl = [&](int bufi, int arr, const u16* g, int r0, int ldg, int k0) {
#pragma unroll
        for (int h = 0; h < 2; ++h) {
            int vt = tid + h * 256;
            int row = vt >> 2;
            int ls = (vt & 3) ^ ((row >> 1) & 3);
            const u16* gp = g + (long)(r0 + row) * ldg + (k0 + 8 * ls);
            u16* lp = &lds[bufi][arr * 4096 + (vt >> 6) * 512];
            gl16(gp, lp);
        }
    };

    auto stage_a_f32 = [&](int bufi, const float* g, int ldg, int kk) {
        int r = tid >> 1;
        int hf = (tid & 1) * 16;
        const float* p = g + (long)(m0 + r) * ldg + kk + hf;
        float4 a0 = *(const float4*)(p + 0);
        float4 a1 = *(const float4*)(p + 4);
        float4 a2 = *(const float4*)(p + 8);
        float4 a3 = *(const float4*)(p + 12);
        float fv[16] = {a0.x, a0.y, a0.z, a0.w, a1.x, a1.y, a1.z, a1.w,
                        a2.x, a2.y, a2.z, a2.w, a3.x, a3.y, a3.z, a3.w};
        u16 hb[16], lb[16];
#pragma unroll
        for (int i = 0; i < 16; ++i) {
            if constexpr (PREC == 0)
                split_bf(fv[i], hb[i], lb[i]);
            else
                hb[i] = __builtin_bit_cast(u16, (_Float16)fv[i]);
        }
        int sw = (r >> 1) & 3;
        int ls0 = hf >> 3;
        u32x4 h0 = {(u32)hb[0] | ((u32)hb[1] << 16), (u32)hb[2] | ((u32)hb[3] << 16),
                    (u32)hb[4] | ((u32)hb[5] << 16), (u32)hb[6] | ((u32)hb[7] << 16)};
        u32x4 h1 = {(u32)hb[8] | ((u32)hb[9] << 16), (u32)hb[10] | ((u32)hb[11] << 16),
                    (u32)hb[12] | ((u32)hb[13] << 16), (u32)hb[14] | ((u32)hb[15] << 16)};
        u16* ah = &lds[bufi][AH * 4096 + r * 32];
        *(u32x4*)(ah + (((ls0 + 0) ^ sw) << 3)) = h0;
        *(u32x4*)(ah + (((ls0 + 1) ^ sw) << 3)) = h1;
        if constexpr (TERMS == 3) {
            u32x4 l0 = {(u32)lb[0] | ((u32)lb[1] << 16), (u32)lb[2] | ((u32)lb[3] << 16),
                        (u32)lb[4] | ((u32)lb[5] << 16), (u32)lb[6] | ((u32)lb[7] << 16)};
            u32x4 l1 = {(u32)lb[8] | ((u32)lb[9] << 16), (u32)lb[10] | ((u32)lb[11] << 16),
                        (u32)lb[12] | ((u32)lb[13] << 16), (u32)lb[14] | ((u32)lb[15] << 16)};
            u16* al = &lds[bufi][AL * 4096 + r * 32];
            *(u32x4*)(al + (((ls0 + 0) ^ sw) << 3)) = l0;
            *(u32x4*)(al + (((ls0 + 1) ^ sw) << 3)) = l1;
        }
    };

    auto stage = [&](int bufi, int t) {
        int k0 = t * 32;
        stage_gl(bufi, BH, Bhi, n0, ldb, k0);
        if (TERMS == 3) stage_gl(bufi, BL, Blo, n0, ldb, k0);
        if (ASRC == 0) {
            stage_gl(bufi, AH, Ahi, m0, lda, k0);
            if (TERMS == 3) stage_gl(bufi, AL, Alo, m0, lda, k0);
        } else {
            stage_a_f32(bufi, Af, lda, k0);
        }
    };

    const int NT = K / 32;
    stage(0, 0);
    __syncthreads();
    int cur = 0;
    using FT = typename FragT<PREC>::T;
    for (int t = 0; t < NT; ++t) {
        if (t + 1 < NT) stage(cur ^ 1, t + 1);

        const u16* L = lds[cur];
        FT afh[4], afl[4], bfh[4], bfl[4];
#pragma unroll
        for (int i = 0; i < 4; ++i) {
            int ra = wm + i * 16 + fr;
            int rb = wn + i * 16 + fr;
            int oa = ra * 32 + ((kq ^ ((ra >> 1) & 3)) << 3);
            int ob = rb * 32 + ((kq ^ ((rb >> 1) & 3)) << 3);
            afh[i] = *(const FT*)(L + AH * 4096 + oa);
            bfh[i] = *(const FT*)(L + BH * 4096 + ob);
            if (TERMS == 3) {
                afl[i] = *(const FT*)(L + AL * 4096 + oa);
                bfl[i] = *(const FT*)(L + BL * 4096 + ob);
            }
        }
#pragma unroll
        for (int i = 0; i < 4; ++i)
#pragma unroll
            for (int j = 0; j < 4; ++j) {
                acc[i][j] = mfma16(afh[i], bfh[j], acc[i][j]);
                if (TERMS == 3) {
                    acc[i][j] = mfma16(afl[i], bfh[j], acc[i][j]);
                    acc[i][j] = mfma16(afh[i], bfl[j], acc[i][j]);
                }
            }
        __syncthreads();
        cur ^= 1;
    }

    long obase = (long)bz * sC + (long)kh * sKh;
    int fq = (lane >> 4) * 4;
#pragma unroll
    for (int i = 0; i < 4; ++i)
#pragma unroll
        for (int j = 0; j < 4; ++j)
#pragma unroll
            for (int g = 0; g < 4; ++g) {
                int row = m0 + wm + i * 16 + fq + g;
                int col = n0 + wn + j * 16 + fr;
                long idx = obase + (long)row * N + col;
                float v = acc[i][j][g];
                if constexpr (EPI == 1) {
                    u16 h2, l2;
                    split_bf(v, h2, l2);
                    Chi[idx] = h2;
                    Clo[idx] = l2;
                } else if constexpr (EPI == 2) {
                    float x = v + bias[col];
                    float t2 = __expf(2.f * x);
                    C[idx] = 1.f - 2.f * __builtin_amdgcn_rcpf(t2 + 1.f);
                } else {
                    Chi[idx] = __builtin_bit_cast(u16, (_Float16)v);
                }
            }
}

extern "C" void kernel_launch(void* const* d_in, const int* in_sizes, int n_in,
                              void* d_out, int out_size, void* d_ws, size_t ws_size,
                              hipStream_t stream) {
    const float* ht = (const float*)d_in[0];
    const float* hs = (const float*)d_in[1];
    const int* source = (const int*)d_in[2];
    const float* Wa = (const float*)d_in[3];
    const float* Wc = (const float*)d_in[4];
    const float* bias = (const float*)d_in[5];
    float* out = (float*)d_out;

    char* w = (char*)d_ws;
    size_t off = 0;
    auto alloc = [&](size_t bytes) -> void* {
        void* p = w + off;
        off += (bytes + 255) & ~(size_t)255;
        return p;
    };
    int* lens = (int*)alloc(256);
    u16* keysHi = (u16*)alloc((size_t)BB * TS * HH * 2);  // 16.78 MB (bf16)
    u16* keysLo = (u16*)alloc((size_t)BB * TS * HH * 2);
    u16* hsRHi = (u16*)alloc((size_t)BB * TS * HH * 2);   // dead after G1
    u16* hsRLo = (u16*)alloc((size_t)BB * TS * HH * 2);
    u16* hsTHi = (u16*)alloc((size_t)BB * HH * TS * 2);   // f16; dead after G3
    u16* WaTHi = (u16*)alloc((size_t)HH * HH * 2);
    u16* WaTLo = (u16*)alloc((size_t)HH * HH * 2);
    // total ~88.1 MB (proven since r2). Overlays (identical to r6/r8/r11):
    u16* scoreH0 = hsRHi;
    u16* scoreH1 = hsRHi + (size_t)BB * TT * TS;
    u16* scoreL0 = hsRLo;
    u16* scoreL1 = hsRLo + (size_t)BB * TT * TS;
    u16* cHi = keysHi;
    u16* WcTHi = scoreL0;
    u16* htF = hsTHi;
    u16* prob = scoreH0;

    // prep1: hs_prep (8192) | WaT transpose (1024) | lens (16) in one launch
    prep1_kernel<<<8192 + 1024 + 16, 256, 0, stream>>>(
        hs, hsRHi, hsRLo, hsTHi, Wa, WaTHi, WaTLo, source, lens);

    // G1: keys = hs @ Wa  (bf16 3-term, 3-ring gemm_p, XCD swz) [measured 55 us]
    gemm_p<0, 3, 1, 0, 1, 1><<<256, 512, 0, stream>>>(
        hsRHi, hsRLo, nullptr, WaTHi, WaTLo,
        nullptr, keysHi, keysLo, nullptr,
        HH, HH, HH, HH, 0, 0, 0, 0);

    // G2: score[b] = ht[b] @ keys[b]^T  (bf16 3-term, 2-phase gemm_u, split-K=2)
    gemm_u<0, 1, 1, 3, 2, false><<<dim3(TS / 128, TT / 128, 2 * BB), 256, 0, stream>>>(
        nullptr, nullptr, ht, keysHi, keysLo,
        nullptr, scoreH0, scoreL0, nullptr,
        TT, TS, HH / 2, HH, HH,
        (long)TT * HH, (long)TS * HH, (long)TT * TS, (long)BB * TT * TS);

    softmax_mask_kernel<<<BB * TT, 64, 0, stream>>>(scoreH0, scoreL0, scoreH1, scoreL1, lens);

    // G3: c[b] = prob[b] @ hs[b]  (f16 1-term, 2-phase gemm_u)
    gemm_u<1, 0, 3, 1, 1, false><<<dim3(HH / 128, TT / 128, BB), 256, 0, stream>>>(
        prob, nullptr, nullptr, hsTHi, nullptr,
        nullptr, cHi, nullptr, nullptr,
        TT, HH, TS, TS, TS,
        (long)TT * TS, (long)HH * TS, (long)TT * HH, 0);

    // prep2: htF f16 (4096) | WcT f16 transpose (2048) in one launch
    prep2_kernel<<<4096 + 2048, 256, 0, stream>>>(ht, htF, Wc, WcTHi);

    // G4: out = tanh(concat(c, ht) @ Wc + b)  (f16 1-term, gemm_p ACON, XCD swz)
    gemm_p<1, 1, 2, 1, 1, 1><<<256, 512, 0, stream>>>(
        cHi, nullptr, htF, WcTHi, nullptr,
        out, nullptr, nullptr, bias,
        OO, 2 * HH, HH, 2 * HH, 0, 0, 0, 0);
}

// Round 14
// 183.309 us; speedup vs baseline: 1.4571x; 1.0376x over previous
//
#include <hip/hip_runtime.h>
#include <math.h>

typedef unsigned short u16;
typedef unsigned int u32;

using f32x4 = __attribute__((ext_vector_type(4))) float;
using s16x8 = __attribute__((ext_vector_type(8))) short;
using f16x8 = __attribute__((ext_vector_type(8))) _Float16;
using u32x4 = __attribute__((ext_vector_type(4))) u32;

#define DEVI static __device__ __forceinline__

// ---- problem constants ----
#define BB 16
#define TT 512
#define TS 512
#define HH 1024
#define OO 1024

// bf16 split: x = hi + lo + eps, |eps| <= 2^-16 |x|
DEVI void split_bf(float x, u16& hb, u16& lb) {
    u32 xb = __float_as_uint(x);
    float hf = __uint_as_float(xb & 0xffff0000u);
    hb = (u16)(xb >> 16);
    lb = (u16)(__float_as_uint(x - hf) >> 16);
}

DEVI float ub(u16 h) { return __uint_as_float((u32)h << 16); }

template <int PREC> struct FragT;
template <> struct FragT<0> { using T = s16x8; };
template <> struct FragT<1> { using T = f16x8; };

DEVI f32x4 mfma16(s16x8 a, s16x8 b, f32x4 c) {
    return __builtin_amdgcn_mfma_f32_16x16x32_bf16(a, b, c, 0, 0, 0);
}
DEVI f32x4 mfma16(f16x8 a, f16x8 b, f32x4 c) {
    return __builtin_amdgcn_mfma_f32_16x16x32_f16(a, b, c, 0, 0, 0);
}

// async global->LDS, 16B/lane; LDS dest wave-uniform base + lane*16
DEVI void gl16(const void* g, void* l) {
    __builtin_amdgcn_global_load_lds(
        (__attribute__((address_space(1))) const void*)g,
        (__attribute__((address_space(3))) void*)l, 16, 0, 0);
}

// ==== fused prep 1: hs_prep (8192) | WaT (1024) | lens (16) | WcT f16 (2048) ====
__global__ void prep1_kernel(const float* __restrict__ hs,
                             u16* __restrict__ rhi, u16* __restrict__ rlo,
                             u16* __restrict__ thi,
                             const float* __restrict__ Wa,
                             u16* __restrict__ whi, u16* __restrict__ wlo,
                             const int* __restrict__ src, int* __restrict__ lens,
                             const float* __restrict__ Wc, u16* __restrict__ wcthi) {
    __shared__ float tile[32][33];
    __shared__ int part[4];
    int id = blockIdx.x;
    int tid = threadIdx.x;
    int tx = tid & 31, ty = tid >> 5;  // 32 x 8
    if (id < 8192) {
        // hs prep: hsR row-major bf16 hi/lo + hsT [HH][TS] f16
        int bx = id & 31, by = (id >> 5) & 15, bz = id >> 9;
        long boff = (long)bz * TS * HH;
        const float* s = hs + boff;
        u16* rh = rhi + boff;
        u16* rl = rlo + boff;
        u16* th = thi + boff;
        int c0 = bx * 32, r0 = by * 32;
#pragma unroll
        for (int i = 0; i < 32; i += 8) {
            long o = (long)(r0 + ty + i) * HH + (c0 + tx);
            float v = s[o];
            tile[ty + i][tx] = v;
            u16 hb, lb;
            split_bf(v, hb, lb);
            rh[o] = hb;
            rl[o] = lb;
        }
        __syncthreads();
#pragma unroll
        for (int i = 0; i < 32; i += 8) {
            long o = (long)(c0 + ty + i) * TS + (r0 + tx);
            th[o] = __builtin_bit_cast(u16, (_Float16)tile[tx][ty + i]);
        }
    } else if (id < 8192 + 1024) {
        // WaT: transpose fp32 [1024][1024] -> split bf16
        int id2 = id - 8192;
        int bx = id2 & 31, by = id2 >> 5;
        int c0 = bx * 32, r0 = by * 32;
#pragma unroll
        for (int i = 0; i < 32; i += 8)
            tile[ty + i][tx] = Wa[(long)(r0 + ty + i) * HH + (c0 + tx)];
        __syncthreads();
#pragma unroll
        for (int i = 0; i < 32; i += 8) {
            u16 hb, lb;
            split_bf(tile[tx][ty + i], hb, lb);
            long o = (long)(c0 + ty + i) * HH + (r0 + tx);
            whi[o] = hb;
            wlo[o] = lb;
        }
    } else if (id < 8192 + 1024 + 16) {
        // lens[b] = count of non-zero source tokens
        int b = id - (8192 + 1024);
        int v0 = (src[b * TS + tid] != 0) ? 1 : 0;
        int v1 = (src[b * TS + 256 + tid] != 0) ? 1 : 0;
        unsigned long long m0 = __ballot(v0);
        unsigned long long m1 = __ballot(v1);
        if ((tid & 63) == 0) part[tid >> 6] = __popcll(m0) + __popcll(m1);
        __syncthreads();
        if (tid == 0) lens[b] = part[0] + part[1] + part[2] + part[3];
    } else {
        // WcT: transpose fp32 [2048][1024] -> f16 [1024][2048] (no deps on G1-G3)
        int id2 = id - (8192 + 1024 + 16);
        int bx = id2 & 31, by = id2 >> 5;  // bx: OO/32, by: 2HH/32
        int c0 = bx * 32, r0 = by * 32;
#pragma unroll
        for (int i = 0; i < 32; i += 8)
            tile[ty + i][tx] = Wc[(long)(r0 + ty + i) * OO + (c0 + tx)];
        __syncthreads();
#pragma unroll
        for (int i = 0; i < 32; i += 8) {
            long o = (long)(c0 + ty + i) * (2 * HH) + (r0 + tx);
            wcthi[o] = __builtin_bit_cast(u16, (_Float16)tile[tx][ty + i]);
        }
    }
}

// ==== fused: masked softmax (2048 blocks, 4 rows each) | htF f16 (4096 blocks) ====
// softmax: full score = (h0+l0)+(h1+l1) bf16 parts, 1 wave/row, 4 waves/block.
// rowmax over FULL row, exp, prefix mask, normalize; writes f16 prob into h0.
// htF: ht fp32 -> f16 row-major, into the keysLo region (dead after G2).
__global__ void softmax_htf_kernel(u16* __restrict__ h0, u16* __restrict__ l0,
                                   const u16* __restrict__ h1, const u16* __restrict__ l1,
                                   const int* __restrict__ lens,
                                   const float* __restrict__ ht, u16* __restrict__ htF) {
    int id = blockIdx.x;
    int tid = threadIdx.x;
    if (id < 2048) {
        long row = (long)id * 4 + (tid >> 6);
        int len = lens[row >> 9];  // TT = 512
        int lane = tid & 63;
        long o = row * TS + 8 * lane;
        s16x8 vh0 = *(const s16x8*)(h0 + o);
        s16x8 vl0 = *(const s16x8*)(l0 + o);
        s16x8 vh1 = *(const s16x8*)(h1 + o);
        s16x8 vl1 = *(const s16x8*)(l1 + o);
        float f[8];
#pragma unroll
        for (int i = 0; i < 8; ++i)
            f[i] = (ub((u16)vh0[i]) + ub((u16)vl0[i])) + (ub((u16)vh1[i]) + ub((u16)vl1[i]));
        float m = f[0];
#pragma unroll
        for (int i = 1; i < 8; ++i) m = fmaxf(m, f[i]);
#pragma unroll
        for (int os = 32; os > 0; os >>= 1) m = fmaxf(m, __shfl_xor(m, os));
        float e[8];
        float sum = 0.f;
#pragma unroll
        for (int i = 0; i < 8; ++i) {
            e[i] = (8 * lane + i < len) ? expf(f[i] - m) : 0.f;
            sum += e[i];
        }
#pragma unroll
        for (int os = 32; os > 0; os >>= 1) sum += __shfl_xor(sum, os);
        float inv = 1.0f / sum;
        f16x8 p;
#pragma unroll
        for (int i = 0; i < 8; ++i) p[i] = (_Float16)(e[i] * inv);
        *(f16x8*)(h0 + o) = p;
    } else {
        long i = ((long)(id - 2048) * 256 + tid) * 8;
        float4 v0 = *(const float4*)(ht + i);
        float4 v1 = *(const float4*)(ht + i + 4);
        float fv[8] = {v0.x, v0.y, v0.z, v0.w, v1.x, v1.y, v1.z, v1.w};
        f16x8 o;
#pragma unroll
        for (int j = 0; j < 8; ++j) o[j] = (_Float16)fv[j];
        *(f16x8*)(htF + i) = o;
    }
}

// ============ deep-pipelined GEMM (r8/r11-proven): BM=256 x BN=128, 8 waves, 3-buf ring ============
// Monolithic per-iter schedule. All operands pre-split u16, pure global_load_lds
// (r12 lesson: B must stay on the gl_lds path — plain B loads share the vmcnt
// counter with the A prefetch and force full drains every sub-step, -78%).
// TERMS=3 (bf16, BK=32) or TERMS=1 (f16, BK=64 = 2 subs). Per iter: issue
// stage(t+2), ds_read frags(buf t), MFMA (setprio), s_waitcnt vmcnt(6)
// [never 0 mid-loop], s_barrier.
// LDS swizzle off_u16 = row*32 + 8*(slot ^ ((row>>1)&3)): applied on global src
// for gl_lds (dest linear, rule #21) and on ds_read addrs.
// ACON: A = [Ahi | A2] along k (both pre-split, lda), switch at k=HH.
// EPI: 1 = bf16 split store; 2 = fast-tanh(x+bias) fp32; 3 = f16 store
template <int PREC, int TERMS, int EPI, int ACON, int KSPLIT, int SWZ>
__global__ __launch_bounds__(512, 2)
void gemm_p(const u16* __restrict__ Ahi, const u16* __restrict__ Alo,
            const u16* __restrict__ A2,
            const u16* __restrict__ Bhi, const u16* __restrict__ Blo,
            float* __restrict__ C, u16* __restrict__ Chi, u16* __restrict__ Clo,
            const float* __restrict__ bias,
            int N, int K, int lda, int ldb,
            long sA, long sB, long sC, long sKh) {
    constexpr int SUBS = (TERMS == 3) ? 1 : 2;
    constexpr int BKI = 32 * SUBS;
    constexpr int SUBU = (TERMS == 3) ? 24576 : 12288;
    constexpr int BUFU = 24576;  // 48 KB per ring buffer
    constexpr int AHo = 0;
    constexpr int ALof = 8192;
    constexpr int BHo = (TERMS == 3) ? 16384 : 8192;
    constexpr int BLof = 20480;

    __shared__ u16 lds[3 * BUFU];  // 144 KB -> 1 block/CU

    int bx, by, bz = 0;
    if (SWZ) {
        int id = blockIdx.x;  // 256 blocks, 8 XCD chunks of 32
        int ns = ((id & 7) << 5) | (id >> 3);
        by = ns >> 3;
        bx = ns & 7;
    } else {
        bx = blockIdx.x;
        by = blockIdx.y;
        bz = blockIdx.z;
    }
    int kh = 0;
    if (KSPLIT == 2) {
        kh = bz & 1;
        bz >>= 1;
    }
    if (!ACON) {
        Ahi += (long)bz * sA + (long)kh * K;
        if (TERMS == 3) Alo += (long)bz * sA + (long)kh * K;
    }
    Bhi += (long)bz * sB + (long)kh * K;
    if (TERMS == 3) Blo += (long)bz * sB + (long)kh * K;

    int tid = threadIdx.x;
    int lane = tid & 63;
    int wave = tid >> 6;
    int wm = (wave >> 1) * 64;
    int wn = (wave & 1) * 64;
    int fr = lane & 15;
    int kq = lane >> 4;
    int m0 = by * 256;
    int n0 = bx * 128;

    f32x4 acc[4][4];
#pragma unroll
    for (int i = 0; i < 4; ++i)
#pragma unroll
        for (int j = 0; j < 4; ++j) acc[i][j] = (f32x4){0.f, 0.f, 0.f, 0.f};

    auto stage_arr = [&](int dst, const u16* g, int r0, int ldg, int k0, int cnt) {
#pragma unroll
        for (int h = 0; h < cnt; ++h) {
            int vt = tid + h * 512;
            int row = vt >> 2;
            int ls = (vt & 3) ^ ((row >> 1) & 3);
            const u16* gp = g + (long)(r0 + row) * ldg + (k0 + 8 * ls);
            u16* lp = lds + dst + ((tid & ~63) + h * 512) * 8;  // wave-uniform
            gl16(gp, lp);
        }
    };
    // exactly 6 gl16 per thread per stage() for both TERMS variants
    auto stage = [&](int bi, int t) {
#pragma unroll
        for (int s = 0; s < SUBS; ++s) {
            int ks = t * BKI + s * 32;
            int sb = bi * BUFU + s * ((TERMS == 3) ? 0 : SUBU);
            if (ACON) {
                if (ks < HH)
                    stage_arr(sb + AHo, Ahi, m0, lda, ks, 2);
                else
                    stage_arr(sb + AHo, A2, m0, lda, ks - HH, 2);
            } else {
                stage_arr(sb + AHo, Ahi, m0, lda, ks, 2);
                if (TERMS == 3) stage_arr(sb + ALof, Alo, m0, lda, ks, 2);
            }
            stage_arr(sb + BHo, Bhi, n0, ldb, ks, 1);
            if (TERMS == 3) stage_arr(sb + BLof, Blo, n0, ldb, ks, 1);
        }
    };

    const int NTI = K / BKI;
    stage(0, 0);
    stage(1, 1);
    stage(2, 2);
    asm volatile("s_waitcnt vmcnt(12)" ::: "memory");  // buf0 landed; 1,2 in flight
    __builtin_amdgcn_sched_barrier(0);
    __builtin_amdgcn_s_barrier();
    __builtin_amdgcn_sched_barrier(0);

    using FT = typename FragT<PREC>::T;
    for (int t = 0; t < NTI; ++t) {
        if (t >= 1 && t + 2 < NTI) stage((t + 2) % 3, t + 2);

        const u16* Lb = lds + (t % 3) * BUFU;
#pragma unroll
        for (int s = 0; s < SUBS; ++s) {
            const u16* Ls = Lb + s * SUBU;
            FT afh[4], afl[4], bfh[4], bfl[4];
#pragma unroll
            for (int i = 0; i < 4; ++i) {
                int ra = wm + i * 16 + fr;
                int rb = wn + i * 16 + fr;
                int oa = ra * 32 + ((kq ^ ((ra >> 1) & 3)) << 3);
                int ob = rb * 32 + ((kq ^ ((rb >> 1) & 3)) << 3);
                afh[i] = *(const FT*)(Ls + AHo + oa);
                bfh[i] = *(const FT*)(Ls + BHo + ob);
                if (TERMS == 3) {
                    afl[i] = *(const FT*)(Ls + ALof + oa);
                    bfl[i] = *(const FT*)(Ls + BLof + ob);
                }
            }
            __builtin_amdgcn_s_setprio(1);
#pragma unroll
            for (int i = 0; i < 4; ++i)
#pragma unroll
                for (int j = 0; j < 4; ++j) {
                    acc[i][j] = mfma16(afh[i], bfh[j], acc[i][j]);
                    if (TERMS == 3) {
                        acc[i][j] = mfma16(afl[i], bfh[j], acc[i][j]);
                        acc[i][j] = mfma16(afh[i], bfl[j], acc[i][j]);
                    }
                }
            __builtin_amdgcn_s_setprio(0);
        }
        if (t < NTI - 1) {
            __builtin_amdgcn_sched_barrier(0);
            if (t + 2 < NTI)
                asm volatile("s_waitcnt vmcnt(6)" ::: "memory");  // newest stage stays in flight
            else
                asm volatile("s_waitcnt vmcnt(0)" ::: "memory");  // epilogue drain
            __builtin_amdgcn_sched_barrier(0);
            __builtin_amdgcn_s_barrier();
            __builtin_amdgcn_sched_barrier(0);
        }
    }

    long obase = (long)bz * sC + (long)kh * sKh;
    int fq = (lane >> 4) * 4;
#pragma unroll
    for (int i = 0; i < 4; ++i)
#pragma unroll
        for (int j = 0; j < 4; ++j)
#pragma unroll
            for (int g = 0; g < 4; ++g) {
                int row = m0 + wm + i * 16 + fq + g;
                int col = n0 + wn + j * 16 + fr;
                long idx = obase + (long)row * N + col;
                float v = acc[i][j][g];
                if constexpr (EPI == 1) {
                    u16 h2, l2;
                    split_bf(v, h2, l2);
                    Chi[idx] = h2;
                    Clo[idx] = l2;
                } else if constexpr (EPI == 2) {
                    float x = v + bias[col];
                    float t2 = __expf(2.f * x);
                    C[idx] = 1.f - 2.f * __builtin_amdgcn_rcpf(t2 + 1.f);
                } else {
                    Chi[idx] = __builtin_bit_cast(u16, (_Float16)v);
                }
            }
}

// ============ 2-phase GEMM (r6-proven) — G2 (reg-staged fp32 ht) and G3 ============
template <int PREC, int ASRC, int EPI, int TERMS, int KSPLIT, bool SWZ>
__global__ __launch_bounds__(256, 2)
void gemm_u(const u16* __restrict__ Ahi, const u16* __restrict__ Alo,
            const float* __restrict__ Af,
            const u16* __restrict__ Bhi, const u16* __restrict__ Blo,
            float* __restrict__ C, u16* __restrict__ Chi, u16* __restrict__ Clo,
            const float* __restrict__ bias,
            int M, int N, int K, int lda, int ldb,
            long sA, long sB, long sC, long sKh) {
    int bx, by, bz;
    if (SWZ) {
        int id = blockIdx.x;
        int ns = ((id & 7) << 6) | (id >> 3);
        bx = ns & 7;
        by = ns >> 3;
        bz = 0;
    } else {
        bx = blockIdx.x;
        by = blockIdx.y;
        bz = blockIdx.z;
    }
    int kh = 0;
    if (KSPLIT == 2) {
        kh = bz & 1;
        bz >>= 1;
    }
    if (ASRC == 0) {
        Ahi += (long)bz * sA + (long)kh * K;
        if (TERMS == 3) Alo += (long)bz * sA + (long)kh * K;
    } else if (ASRC == 1) {
        Af += (long)bz * sA + (long)kh * K;
    }
    Bhi += (long)bz * sB + (long)kh * K;
    if (TERMS == 3) Blo += (long)bz * sB + (long)kh * K;

    int n0 = bx * 128;
    int m0 = by * 128;

    constexpr int NARR = (TERMS == 3) ? 4 : 2;
    constexpr int AH = 0, AL = 1;
    constexpr int BH = (TERMS == 3) ? 2 : 1;
    constexpr int BL = 3;
    __shared__ u16 lds[2][NARR * 4096];

    int tid = threadIdx.x;
    int lane = tid & 63;
    int wave = tid >> 6;
    int wm = (wave >> 1) * 64;
    int wn = (wave & 1) * 64;
    int fr = lane & 15;
    int kq = lane >> 4;

    f32x4 acc[4][4];
#pragma unroll
    for (int i = 0; i < 4; ++i)
#pragma unroll
        for (int j = 0; j < 4; ++j) acc[i][j] = (f32x4){0.f, 0.f, 0.f, 0.f};

    auto stage_gl = [&](int bufi, int arr, const u16* g, int r0, int ldg, int k0) {
#pragma unroll
        for (int h = 0; h < 2; ++h) {
            int vt = tid + h * 256;
            int row = vt >> 2;
            int ls = (vt & 3) ^ ((row >> 1) & 3);
            const u16* gp = g + (long)(r0 + row) * ldg + (k0 + 8 * ls);
            u16* lp = &lds[bufi][arr * 4096 + (vt >> 6) * 512];
            gl16(gp, lp);
        }
    };

    auto stage_a_f32 = [&](int bufi, const float* g, int ldg, int kk) {
        int r = tid >> 1;
        int hf = (tid & 1) * 16;
        const float* p = g + (long)(m0 + r) * ldg + kk + hf;
        float4 a0 = *(const float4*)(p + 0);
        float4 a1 = *(const float4*)(p + 4);
        float4 a2 = *(const float4*)(p + 8);
        float4 a3 = *(const float4*)(p + 12);
        float fv[16] = {a0.x, a0.y, a0.z, a0.w, a1.x, a1.y, a1.z, a1.w,
                        a2.x, a2.y, a2.z, a2.w, a3.x, a3.y, a3.z, a3.w};
        u16 hb[16], lb[16];
#pragma unroll
        for (int i = 0; i < 16; ++i) {
            if constexpr (PREC == 0)
                split_bf(fv[i], hb[i], lb[i]);
            else
                hb[i] = __builtin_bit_cast(u16, (_Float16)fv[i]);
        }
        int sw = (r >> 1) & 3;
        int ls0 = hf >> 3;
        u32x4 h0 = {(u32)hb[0] | ((u32)hb[1] << 16), (u32)hb[2] | ((u32)hb[3] << 16),
                    (u32)hb[4] | ((u32)hb[5] << 16), (u32)hb[6] | ((u32)hb[7] << 16)};
        u32x4 h1 = {(u32)hb[8] | ((u32)hb[9] << 16), (u32)hb[10] | ((u32)hb[11] << 16),
                    (u32)hb[12] | ((u32)hb[13] << 16), (u32)hb[14] | ((u32)hb[15] << 16)};
        u16* ah = &lds[bufi][AH * 4096 + r * 32];
        *(u32x4*)(ah + (((ls0 + 0) ^ sw) << 3)) = h0;
        *(u32x4*)(ah + (((ls0 + 1) ^ sw) << 3)) = h1;
        if constexpr (TERMS == 3) {
            u32x4 l0 = {(u32)lb[0] | ((u32)lb[1] << 16), (u32)lb[2] | ((u32)lb[3] << 16),
                        (u32)lb[4] | ((u32)lb[5] << 16), (u32)lb[6] | ((u32)lb[7] << 16)};
            u32x4 l1 = {(u32)lb[8] | ((u32)lb[9] << 16), (u32)lb[10] | ((u32)lb[11] << 16),
                        (u32)lb[12] | ((u32)lb[13] << 16), (u32)lb[14] | ((u32)lb[15] << 16)};
            u16* al = &lds[bufi][AL * 4096 + r * 32];
            *(u32x4*)(al + (((ls0 + 0) ^ sw) << 3)) = l0;
            *(u32x4*)(al + (((ls0 + 1) ^ sw) << 3)) = l1;
        }
    };

    auto stage = [&](int bufi, int t) {
        int k0 = t * 32;
        stage_gl(bufi, BH, Bhi, n0, ldb, k0);
        if (TERMS == 3) stage_gl(bufi, BL, Blo, n0, ldb, k0);
        if (ASRC == 0) {
            stage_gl(bufi, AH, Ahi, m0, lda, k0);
            if (TERMS == 3) stage_gl(bufi, AL, Alo, m0, lda, k0);
        } else {
            stage_a_f32(bufi, Af, lda, k0);
        }
    };

    const int NT = K / 32;
    stage(0, 0);
    __syncthreads();
    int cur = 0;
    using FT = typename FragT<PREC>::T;
    for (int t = 0; t < NT; ++t) {
        if (t + 1 < NT) stage(cur ^ 1, t + 1);

        const u16* L = lds[cur];
        FT afh[4], afl[4], bfh[4], bfl[4];
#pragma unroll
        for (int i = 0; i < 4; ++i) {
            int ra = wm + i * 16 + fr;
            int rb = wn + i * 16 + fr;
            int oa = ra * 32 + ((kq ^ ((ra >> 1) & 3)) << 3);
            int ob = rb * 32 + ((kq ^ ((rb >> 1) & 3)) << 3);
            afh[i] = *(const FT*)(L + AH * 4096 + oa);
            bfh[i] = *(const FT*)(L + BH * 4096 + ob);
            if (TERMS == 3) {
                afl[i] = *(const FT*)(L + AL * 4096 + oa);
                bfl[i] = *(const FT*)(L + BL * 4096 + ob);
            }
        }
#pragma unroll
        for (int i = 0; i < 4; ++i)
#pragma unroll
            for (int j = 0; j < 4; ++j) {
                acc[i][j] = mfma16(afh[i], bfh[j], acc[i][j]);
                if (TERMS == 3) {
                    acc[i][j] = mfma16(afl[i], bfh[j], acc[i][j]);
                    acc[i][j] = mfma16(afh[i], bfl[j], acc[i][j]);
                }
            }
        __syncthreads();
        cur ^= 1;
    }

    long obase = (long)bz * sC + (long)kh * sKh;
    int fq = (lane >> 4) * 4;
#pragma unroll
    for (int i = 0; i < 4; ++i)
#pragma unroll
        for (int j = 0; j < 4; ++j)
#pragma unroll
            for (int g = 0; g < 4; ++g) {
                int row = m0 + wm + i * 16 + fq + g;
                int col = n0 + wn + j * 16 + fr;
                long idx = obase + (long)row * N + col;
                float v = acc[i][j][g];
                if constexpr (EPI == 1) {
                    u16 h2, l2;
                    split_bf(v, h2, l2);
                    Chi[idx] = h2;
                    Clo[idx] = l2;
                } else if constexpr (EPI == 2) {
                    float x = v + bias[col];
                    float t2 = __expf(2.f * x);
                    C[idx] = 1.f - 2.f * __builtin_amdgcn_rcpf(t2 + 1.f);
                } else {
                    Chi[idx] = __builtin_bit_cast(u16, (_Float16)v);
                }
            }
}

extern "C" void kernel_launch(void* const* d_in, const int* in_sizes, int n_in,
                              void* d_out, int out_size, void* d_ws, size_t ws_size,
                              hipStream_t stream) {
    const float* ht = (const float*)d_in[0];
    const float* hs = (const float*)d_in[1];
    const int* source = (const int*)d_in[2];
    const float* Wa = (const float*)d_in[3];
    const float* Wc = (const float*)d_in[4];
    const float* bias = (const float*)d_in[5];
    float* out = (float*)d_out;

    char* w = (char*)d_ws;
    size_t off = 0;
    auto alloc = [&](size_t bytes) -> void* {
        void* p = w + off;
        off += (bytes + 255) & ~(size_t)255;
        return p;
    };
    int* lens = (int*)alloc(256);
    u16* keysHi = (u16*)alloc((size_t)BB * TS * HH * 2);  // 16.78 MB (bf16)
    u16* keysLo = (u16*)alloc((size_t)BB * TS * HH * 2);
    u16* hsRHi = (u16*)alloc((size_t)BB * TS * HH * 2);   // dead after G1
    u16* hsRLo = (u16*)alloc((size_t)BB * TS * HH * 2);
    u16* hsTHi = (u16*)alloc((size_t)BB * HH * TS * 2);   // f16; G3's B
    u16* WaTHi = (u16*)alloc((size_t)HH * HH * 2);
    u16* WaTLo = (u16*)alloc((size_t)HH * HH * 2);
    u16* WcTHi = (u16*)alloc((size_t)2 * HH * OO * 2);    // f16; dedicated (4.2 MB)
    // total ~92.3 MB (<= 96.5 MB proven in round 1). Overlays:
    //   score H0|H1 -> hsRHi;  L0|L1 -> hsRLo   (hsR dead after G1)
    //   cHi f16 -> keysHi                        (keysHi dead after G2)
    //   htF f16 -> keysLo                        (keysLo dead after G2)
    u16* scoreH0 = hsRHi;
    u16* scoreH1 = hsRHi + (size_t)BB * TT * TS;
    u16* scoreL0 = hsRLo;
    u16* scoreL1 = hsRLo + (size_t)BB * TT * TS;
    u16* cHi = keysHi;
    u16* htF = keysLo;
    u16* prob = scoreH0;

    // prep1: hs_prep (8192) | WaT (1024) | lens (16) | WcT (2048) in one launch
    prep1_kernel<<<8192 + 1024 + 16 + 2048, 256, 0, stream>>>(
        hs, hsRHi, hsRLo, hsTHi, Wa, WaTHi, WaTLo, source, lens, Wc, WcTHi);

    // G1: keys = hs @ Wa  (bf16 3-term, 3-ring gemm_p, XCD swz) [measured 55 us]
    gemm_p<0, 3, 1, 0, 1, 1><<<256, 512, 0, stream>>>(
        hsRHi, hsRLo, nullptr, WaTHi, WaTLo,
        nullptr, keysHi, keysLo, nullptr,
        HH, HH, HH, HH, 0, 0, 0, 0);

    // G2: score[b] = ht[b] @ keys[b]^T  (bf16 3-term, 2-phase gemm_u, split-K=2)
    gemm_u<0, 1, 1, 3, 2, false><<<dim3(TS / 128, TT / 128, 2 * BB), 256, 0, stream>>>(
        nullptr, nullptr, ht, keysHi, keysLo,
        nullptr, scoreH0, scoreL0, nullptr,
        TT, TS, HH / 2, HH, HH,
        (long)TT * HH, (long)TS * HH, (long)TT * TS, (long)BB * TT * TS);

    // softmax (2048 blocks, 4 rows each) | htF f16 -> keysLo (4096 blocks), fused
    softmax_htf_kernel<<<2048 + 4096, 256, 0, stream>>>(
        scoreH0, scoreL0, scoreH1, scoreL1, lens, ht, htF);

    // G3: c[b] = prob[b] @ hs[b]  (f16 1-term, 2-phase gemm_u)
    gemm_u<1, 0, 3, 1, 1, false><<<dim3(HH / 128, TT / 128, BB), 256, 0, stream>>>(
        prob, nullptr, nullptr, hsTHi, nullptr,
        nullptr, cHi, nullptr, nullptr,
        TT, HH, TS, TS, TS,
        (long)TT * TS, (long)HH * TS, (long)TT * HH, 0);

    // G4: out = tanh(concat(c, ht) @ Wc + b)  (f16 1-term, gemm_p ACON, XCD swz)
    gemm_p<1, 1, 2, 1, 1, 1><<<256, 512, 0, stream>>>(
        cHi, nullptr, htF, WcTHi, nullptr,
        out, nullptr, nullptr, bias,
        OO, 2 * HH, HH, 2 * HH, 0, 0, 0, 0);
}

// Round 15
// 182.430 us; speedup vs baseline: 1.4641x; 1.0048x over previous
//
#include <hip/hip_runtime.h>
#include <math.h>

typedef unsigned short u16;
typedef unsigned int u32;

using f32x4 = __attribute__((ext_vector_type(4))) float;
using s16x8 = __attribute__((ext_vector_type(8))) short;
using f16x8 = __attribute__((ext_vector_type(8))) _Float16;
using u32x4 = __attribute__((ext_vector_type(4))) u32;

#define DEVI static __device__ __forceinline__

// ---- problem constants ----
#define BB 16
#define TT 512
#define TS 512
#define HH 1024
#define OO 1024

// bf16 split: x = hi + lo + eps, |eps| <= 2^-16 |x|
DEVI void split_bf(float x, u16& hb, u16& lb) {
    u32 xb = __float_as_uint(x);
    float hf = __uint_as_float(xb & 0xffff0000u);
    hb = (u16)(xb >> 16);
    lb = (u16)(__float_as_uint(x - hf) >> 16);
}

DEVI float ub(u16 h) { return __uint_as_float((u32)h << 16); }

template <int PREC> struct FragT;
template <> struct FragT<0> { using T = s16x8; };
template <> struct FragT<1> { using T = f16x8; };

DEVI f32x4 mfma16(s16x8 a, s16x8 b, f32x4 c) {
    return __builtin_amdgcn_mfma_f32_16x16x32_bf16(a, b, c, 0, 0, 0);
}
DEVI f32x4 mfma16(f16x8 a, f16x8 b, f32x4 c) {
    return __builtin_amdgcn_mfma_f32_16x16x32_f16(a, b, c, 0, 0, 0);
}

// async global->LDS, 16B/lane; LDS dest wave-uniform base + lane*16
DEVI void gl16(const void* g, void* l) {
    __builtin_amdgcn_global_load_lds(
        (__attribute__((address_space(1))) const void*)g,
        (__attribute__((address_space(3))) void*)l, 16, 0, 0);
}

// ==== fused prep 1: hs_prep (8192) | WaT (1024) | lens (16) | WcT f16 (2048) ====
__global__ void prep1_kernel(const float* __restrict__ hs,
                             u16* __restrict__ rhi, u16* __restrict__ rlo,
                             u16* __restrict__ thi,
                             const float* __restrict__ Wa,
                             u16* __restrict__ whi, u16* __restrict__ wlo,
                             const int* __restrict__ src, int* __restrict__ lens,
                             const float* __restrict__ Wc, u16* __restrict__ wcthi) {
    __shared__ float tile[32][33];
    __shared__ int part[4];
    int id = blockIdx.x;
    int tid = threadIdx.x;
    int tx = tid & 31, ty = tid >> 5;  // 32 x 8
    if (id < 8192) {
        // hs prep: hsR row-major bf16 hi/lo + hsT [HH][TS] f16
        int bx = id & 31, by = (id >> 5) & 15, bz = id >> 9;
        long boff = (long)bz * TS * HH;
        const float* s = hs + boff;
        u16* rh = rhi + boff;
        u16* rl = rlo + boff;
        u16* th = thi + boff;
        int c0 = bx * 32, r0 = by * 32;
#pragma unroll
        for (int i = 0; i < 32; i += 8) {
            long o = (long)(r0 + ty + i) * HH + (c0 + tx);
            float v = s[o];
            tile[ty + i][tx] = v;
            u16 hb, lb;
            split_bf(v, hb, lb);
            rh[o] = hb;
            rl[o] = lb;
        }
        __syncthreads();
#pragma unroll
        for (int i = 0; i < 32; i += 8) {
            long o = (long)(c0 + ty + i) * TS + (r0 + tx);
            th[o] = __builtin_bit_cast(u16, (_Float16)tile[tx][ty + i]);
        }
    } else if (id < 8192 + 1024) {
        // WaT: transpose fp32 [1024][1024] -> split bf16
        int id2 = id - 8192;
        int bx = id2 & 31, by = id2 >> 5;
        int c0 = bx * 32, r0 = by * 32;
#pragma unroll
        for (int i = 0; i < 32; i += 8)
            tile[ty + i][tx] = Wa[(long)(r0 + ty + i) * HH + (c0 + tx)];
        __syncthreads();
#pragma unroll
        for (int i = 0; i < 32; i += 8) {
            u16 hb, lb;
            split_bf(tile[tx][ty + i], hb, lb);
            long o = (long)(c0 + ty + i) * HH + (r0 + tx);
            whi[o] = hb;
            wlo[o] = lb;
        }
    } else if (id < 8192 + 1024 + 16) {
        // lens[b] = count of non-zero source tokens
        int b = id - (8192 + 1024);
        int v0 = (src[b * TS + tid] != 0) ? 1 : 0;
        int v1 = (src[b * TS + 256 + tid] != 0) ? 1 : 0;
        unsigned long long m0 = __ballot(v0);
        unsigned long long m1 = __ballot(v1);
        if ((tid & 63) == 0) part[tid >> 6] = __popcll(m0) + __popcll(m1);
        __syncthreads();
        if (tid == 0) lens[b] = part[0] + part[1] + part[2] + part[3];
    } else {
        // WcT: transpose fp32 [2048][1024] -> f16 [1024][2048] (no deps on G1-G3)
        int id2 = id - (8192 + 1024 + 16);
        int bx = id2 & 31, by = id2 >> 5;  // bx: OO/32, by: 2HH/32
        int c0 = bx * 32, r0 = by * 32;
#pragma unroll
        for (int i = 0; i < 32; i += 8)
            tile[ty + i][tx] = Wc[(long)(r0 + ty + i) * OO + (c0 + tx)];
        __syncthreads();
#pragma unroll
        for (int i = 0; i < 32; i += 8) {
            long o = (long)(c0 + ty + i) * (2 * HH) + (r0 + tx);
            wcthi[o] = __builtin_bit_cast(u16, (_Float16)tile[tx][ty + i]);
        }
    }
}

// ==== fused: masked softmax (2048 blocks, 4 rows each) | htF f16 (4096 blocks) ====
// softmax: full score = (h0+l0)+(h1+l1) bf16 parts, 1 wave/row, 4 waves/block.
// rowmax over FULL row, exp, prefix mask, normalize; writes f16 prob into h0.
// htF: ht fp32 -> f16 row-major, into the keysLo region (dead after G2).
__global__ void softmax_htf_kernel(u16* __restrict__ h0, u16* __restrict__ l0,
                                   const u16* __restrict__ h1, const u16* __restrict__ l1,
                                   const int* __restrict__ lens,
                                   const float* __restrict__ ht, u16* __restrict__ htF) {
    int id = blockIdx.x;
    int tid = threadIdx.x;
    if (id < 2048) {
        long row = (long)id * 4 + (tid >> 6);
        int len = lens[row >> 9];  // TT = 512
        int lane = tid & 63;
        long o = row * TS + 8 * lane;
        s16x8 vh0 = *(const s16x8*)(h0 + o);
        s16x8 vl0 = *(const s16x8*)(l0 + o);
        s16x8 vh1 = *(const s16x8*)(h1 + o);
        s16x8 vl1 = *(const s16x8*)(l1 + o);
        float f[8];
#pragma unroll
        for (int i = 0; i < 8; ++i)
            f[i] = (ub((u16)vh0[i]) + ub((u16)vl0[i])) + (ub((u16)vh1[i]) + ub((u16)vl1[i]));
        float m = f[0];
#pragma unroll
        for (int i = 1; i < 8; ++i) m = fmaxf(m, f[i]);
#pragma unroll
        for (int os = 32; os > 0; os >>= 1) m = fmaxf(m, __shfl_xor(m, os));
        float e[8];
        float sum = 0.f;
#pragma unroll
        for (int i = 0; i < 8; ++i) {
            e[i] = (8 * lane + i < len) ? expf(f[i] - m) : 0.f;
            sum += e[i];
        }
#pragma unroll
        for (int os = 32; os > 0; os >>= 1) sum += __shfl_xor(sum, os);
        float inv = 1.0f / sum;
        f16x8 p;
#pragma unroll
        for (int i = 0; i < 8; ++i) p[i] = (_Float16)(e[i] * inv);
        *(f16x8*)(h0 + o) = p;
    } else {
        long i = ((long)(id - 2048) * 256 + tid) * 8;
        float4 v0 = *(const float4*)(ht + i);
        float4 v1 = *(const float4*)(ht + i + 4);
        float fv[8] = {v0.x, v0.y, v0.z, v0.w, v1.x, v1.y, v1.z, v1.w};
        f16x8 o;
#pragma unroll
        for (int j = 0; j < 8; ++j) o[j] = (_Float16)fv[j];
        *(f16x8*)(htF + i) = o;
    }
}

// ============ deep-pipelined GEMM (r8/r11-proven): BM=256 x BN=128, 8 waves, 3-buf ring ============
// Monolithic per-iter schedule. All operands pre-split u16, pure global_load_lds
// (r12 lesson: B must stay on the gl_lds path — plain B loads share the vmcnt
// counter with the A prefetch and force full drains every sub-step, -78%).
// TERMS=3 (bf16, BK=32) or TERMS=1 (f16, BK=64 = 2 subs). Per iter: issue
// stage(t+2), ds_read frags(buf t), MFMA (setprio), s_waitcnt vmcnt(6)
// [never 0 mid-loop], s_barrier.
// LDS swizzle off_u16 = row*32 + 8*(slot ^ ((row>>1)&3)): applied on global src
// for gl_lds (dest linear, rule #21) and on ds_read addrs.
// ACON: A = [Ahi | A2] along k (both pre-split, lda), switch at k=HH.
// EPI: 1 = bf16 split store; 2 = fast-tanh(x+bias) fp32; 3 = f16 store
template <int PREC, int TERMS, int EPI, int ACON, int KSPLIT, int SWZ>
__global__ __launch_bounds__(512, 2)
void gemm_p(const u16* __restrict__ Ahi, const u16* __restrict__ Alo,
            const u16* __restrict__ A2,
            const u16* __restrict__ Bhi, const u16* __restrict__ Blo,
            float* __restrict__ C, u16* __restrict__ Chi, u16* __restrict__ Clo,
            const float* __restrict__ bias,
            int N, int K, int lda, int ldb,
            long sA, long sB, long sC, long sKh) {
    constexpr int SUBS = (TERMS == 3) ? 1 : 2;
    constexpr int BKI = 32 * SUBS;
    constexpr int SUBU = (TERMS == 3) ? 24576 : 12288;
    constexpr int BUFU = 24576;  // 48 KB per ring buffer
    constexpr int AHo = 0;
    constexpr int ALof = 8192;
    constexpr int BHo = (TERMS == 3) ? 16384 : 8192;
    constexpr int BLof = 20480;

    __shared__ u16 lds[3 * BUFU];  // 144 KB -> 1 block/CU

    int bx, by, bz = 0;
    if (SWZ) {
        int id = blockIdx.x;  // 256 blocks, 8 XCD chunks of 32
        int ns = ((id & 7) << 5) | (id >> 3);
        by = ns >> 3;
        bx = ns & 7;
    } else {
        bx = blockIdx.x;
        by = blockIdx.y;
        bz = blockIdx.z;
    }
    int kh = 0;
    if (KSPLIT == 2) {
        kh = bz & 1;
        bz >>= 1;
    }
    if (!ACON) {
        Ahi += (long)bz * sA + (long)kh * K;
        if (TERMS == 3) Alo += (long)bz * sA + (long)kh * K;
    }
    Bhi += (long)bz * sB + (long)kh * K;
    if (TERMS == 3) Blo += (long)bz * sB + (long)kh * K;

    int tid = threadIdx.x;
    int lane = tid & 63;
    int wave = tid >> 6;
    int wm = (wave >> 1) * 64;
    int wn = (wave & 1) * 64;
    int fr = lane & 15;
    int kq = lane >> 4;
    int m0 = by * 256;
    int n0 = bx * 128;

    f32x4 acc[4][4];
#pragma unroll
    for (int i = 0; i < 4; ++i)
#pragma unroll
        for (int j = 0; j < 4; ++j) acc[i][j] = (f32x4){0.f, 0.f, 0.f, 0.f};

    auto stage_arr = [&](int dst, const u16* g, int r0, int ldg, int k0, int cnt) {
#pragma unroll
        for (int h = 0; h < cnt; ++h) {
            int vt = tid + h * 512;
            int row = vt >> 2;
            int ls = (vt & 3) ^ ((row >> 1) & 3);
            const u16* gp = g + (long)(r0 + row) * ldg + (k0 + 8 * ls);
            u16* lp = lds + dst + ((tid & ~63) + h * 512) * 8;  // wave-uniform
            gl16(gp, lp);
        }
    };
    // exactly 6 gl16 per thread per stage() for both TERMS variants
    auto stage = [&](int bi, int t) {
#pragma unroll
        for (int s = 0; s < SUBS; ++s) {
            int ks = t * BKI + s * 32;
            int sb = bi * BUFU + s * ((TERMS == 3) ? 0 : SUBU);
            if (ACON) {
                if (ks < HH)
                    stage_arr(sb + AHo, Ahi, m0, lda, ks, 2);
                else
                    stage_arr(sb + AHo, A2, m0, lda, ks - HH, 2);
            } else {
                stage_arr(sb + AHo, Ahi, m0, lda, ks, 2);
                if (TERMS == 3) stage_arr(sb + ALof, Alo, m0, lda, ks, 2);
            }
            stage_arr(sb + BHo, Bhi, n0, ldb, ks, 1);
            if (TERMS == 3) stage_arr(sb + BLof, Blo, n0, ldb, ks, 1);
        }
    };

    const int NTI = K / BKI;
    stage(0, 0);
    stage(1, 1);
    stage(2, 2);
    asm volatile("s_waitcnt vmcnt(12)" ::: "memory");  // buf0 landed; 1,2 in flight
    __builtin_amdgcn_sched_barrier(0);
    __builtin_amdgcn_s_barrier();
    __builtin_amdgcn_sched_barrier(0);

    using FT = typename FragT<PREC>::T;
    for (int t = 0; t < NTI; ++t) {
        if (t >= 1 && t + 2 < NTI) stage((t + 2) % 3, t + 2);

        const u16* Lb = lds + (t % 3) * BUFU;
#pragma unroll
        for (int s = 0; s < SUBS; ++s) {
            const u16* Ls = Lb + s * SUBU;
            FT afh[4], afl[4], bfh[4], bfl[4];
#pragma unroll
            for (int i = 0; i < 4; ++i) {
                int ra = wm + i * 16 + fr;
                int rb = wn + i * 16 + fr;
                int oa = ra * 32 + ((kq ^ ((ra >> 1) & 3)) << 3);
                int ob = rb * 32 + ((kq ^ ((rb >> 1) & 3)) << 3);
                afh[i] = *(const FT*)(Ls + AHo + oa);
                bfh[i] = *(const FT*)(Ls + BHo + ob);
                if (TERMS == 3) {
                    afl[i] = *(const FT*)(Ls + ALof + oa);
                    bfl[i] = *(const FT*)(Ls + BLof + ob);
                }
            }
            __builtin_amdgcn_s_setprio(1);
#pragma unroll
            for (int i = 0; i < 4; ++i)
#pragma unroll
                for (int j = 0; j < 4; ++j) {
                    acc[i][j] = mfma16(afh[i], bfh[j], acc[i][j]);
                    if (TERMS == 3) {
                        acc[i][j] = mfma16(afl[i], bfh[j], acc[i][j]);
                        acc[i][j] = mfma16(afh[i], bfl[j], acc[i][j]);
                    }
                }
            __builtin_amdgcn_s_setprio(0);
        }
        if (t < NTI - 1) {
            __builtin_amdgcn_sched_barrier(0);
            if (t + 2 < NTI)
                asm volatile("s_waitcnt vmcnt(6)" ::: "memory");  // newest stage stays in flight
            else
                asm volatile("s_waitcnt vmcnt(0)" ::: "memory");  // epilogue drain
            __builtin_amdgcn_sched_barrier(0);
            __builtin_amdgcn_s_barrier();
            __builtin_amdgcn_sched_barrier(0);
        }
    }

    long obase = (long)bz * sC + (long)kh * sKh;
    int fq = (lane >> 4) * 4;
#pragma unroll
    for (int i = 0; i < 4; ++i)
#pragma unroll
        for (int j = 0; j < 4; ++j)
#pragma unroll
            for (int g = 0; g < 4; ++g) {
                int row = m0 + wm + i * 16 + fq + g;
                int col = n0 + wn + j * 16 + fr;
                long idx = obase + (long)row * N + col;
                float v = acc[i][j][g];
                if constexpr (EPI == 1) {
                    u16 h2, l2;
                    split_bf(v, h2, l2);
                    Chi[idx] = h2;
                    Clo[idx] = l2;
                } else if constexpr (EPI == 2) {
                    float x = v + bias[col];
                    float t2 = __expf(2.f * x);
                    C[idx] = 1.f - 2.f * __builtin_amdgcn_rcpf(t2 + 1.f);
                } else {
                    Chi[idx] = __builtin_bit_cast(u16, (_Float16)v);
                }
            }
}

// ============ 2-phase GEMM (r6-proven) — G2 (reg-staged fp32 ht) and G3 ============
template <int PREC, int ASRC, int EPI, int TERMS, int KSPLIT, bool SWZ>
__global__ __launch_bounds__(256, 2)
void gemm_u(const u16* __restrict__ Ahi, const u16* __restrict__ Alo,
            const float* __restrict__ Af,
            const u16* __restrict__ Bhi, const u16* __restrict__ Blo,
            float* __restrict__ C, u16* __restrict__ Chi, u16* __restrict__ Clo,
            const float* __restrict__ bias,
            int M, int N, int K, int lda, int ldb,
            long sA, long sB, long sC, long sKh) {
    int bx, by, bz;
    if (SWZ) {
        int id = blockIdx.x;
        int ns = ((id & 7) << 6) | (id >> 3);
        bx = ns & 7;
        by = ns >> 3;
        bz = 0;
    } else {
        bx = blockIdx.x;
        by = blockIdx.y;
        bz = blockIdx.z;
    }
    int kh = 0;
    if (KSPLIT == 2) {
        kh = bz & 1;
        bz >>= 1;
    }
    if (ASRC == 0) {
        Ahi += (long)bz * sA + (long)kh * K;
        if (TERMS == 3) Alo += (long)bz * sA + (long)kh * K;
    } else if (ASRC == 1) {
        Af += (long)bz * sA + (long)kh * K;
    }
    Bhi += (long)bz * sB + (long)kh * K;
    if (TERMS == 3) Blo += (long)bz * sB + (long)kh * K;

    int n0 = bx * 128;
    int m0 = by * 128;

    constexpr int NARR = (TERMS == 3) ? 4 : 2;
    constexpr int AH = 0, AL = 1;
    constexpr int BH = (TERMS == 3) ? 2 : 1;
    constexpr int BL = 3;
    __shared__ u16 lds[2][NARR * 4096];

    int tid = threadIdx.x;
    int lane = tid & 63;
    int wave = tid >> 6;
    int wm = (wave >> 1) * 64;
    int wn = (wave & 1) * 64;
    int fr = lane & 15;
    int kq = lane >> 4;

    f32x4 acc[4][4];
#pragma unroll
    for (int i = 0; i < 4; ++i)
#pragma unroll
        for (int j = 0; j < 4; ++j) acc[i][j] = (f32x4){0.f, 0.f, 0.f, 0.f};

    auto stage_gl = [&](int bufi, int arr, const u16* g, int r0, int ldg, int k0) {
#pragma unroll
        for (int h = 0; h < 2; ++h) {
            int vt = tid + h * 256;
            int row = vt >> 2;
            int ls = (vt & 3) ^ ((row >> 1) & 3);
            const u16* gp = g + (long)(r0 + row) * ldg + (k0 + 8 * ls);
            u16* lp = &lds[bufi][arr * 4096 + (vt >> 6) * 512];
            gl16(gp, lp);
        }
    };

    auto stage_a_f32 = [&](int bufi, const float* g, int ldg, int kk) {
        int r = tid >> 1;
        int hf = (tid & 1) * 16;
        const float* p = g + (long)(m0 + r) * ldg + kk + hf;
        float4 a0 = *(const float4*)(p + 0);
        float4 a1 = *(const float4*)(p + 4);
        float4 a2 = *(const float4*)(p + 8);
        float4 a3 = *(const float4*)(p + 12);
        float fv[16] = {a0.x, a0.y, a0.z, a0.w, a1.x, a1.y, a1.z, a1.w,
                        a2.x, a2.y, a2.z, a2.w, a3.x, a3.y, a3.z, a3.w};
        u16 hb[16], lb[16];
#pragma unroll
        for (int i = 0; i < 16; ++i) {
            if constexpr (PREC == 0)
                split_bf(fv[i], hb[i], lb[i]);
            else
                hb[i] = __builtin_bit_cast(u16, (_Float16)fv[i]);
        }
        int sw = (r >> 1) & 3;
        int ls0 = hf >> 3;
        u32x4 h0 = {(u32)hb[0] | ((u32)hb[1] << 16), (u32)hb[2] | ((u32)hb[3] << 16),
                    (u32)hb[4] | ((u32)hb[5] << 16), (u32)hb[6] | ((u32)hb[7] << 16)};
        u32x4 h1 = {(u32)hb[8] | ((u32)hb[9] << 16), (u32)hb[10] | ((u32)hb[11] << 16),
                    (u32)hb[12] | ((u32)hb[13] << 16), (u32)hb[14] | ((u32)hb[15] << 16)};
        u16* ah = &lds[bufi][AH * 4096 + r * 32];
        *(u32x4*)(ah + (((ls0 + 0) ^ sw) << 3)) = h0;
        *(u32x4*)(ah + (((ls0 + 1) ^ sw) << 3)) = h1;
        if constexpr (TERMS == 3) {
            u32x4 l0 = {(u32)lb[0] | ((u32)lb[1] << 16), (u32)lb[2] | ((u32)lb[3] << 16),
                        (u32)lb[4] | ((u32)lb[5] << 16), (u32)lb[6] | ((u32)lb[7] << 16)};
            u32x4 l1 = {(u32)lb[8] | ((u32)lb[9] << 16), (u32)lb[10] | ((u32)lb[11] << 16),
                        (u32)lb[12] | ((u32)lb[13] << 16), (u32)lb[14] | ((u32)lb[15] << 16)};
            u16* al = &lds[bufi][AL * 4096 + r * 32];
            *(u32x4*)(al + (((ls0 + 0) ^ sw) << 3)) = l0;
            *(u32x4*)(al + (((ls0 + 1) ^ sw) << 3)) = l1;
        }
    };

    auto stage = [&](int bufi, int t) {
        int k0 = t * 32;
        stage_gl(bufi, BH, Bhi, n0, ldb, k0);
        if (TERMS == 3) stage_gl(bufi, BL, Blo, n0, ldb, k0);
        if (ASRC == 0) {
            stage_gl(bufi, AH, Ahi, m0, lda, k0);
            if (TERMS == 3) stage_gl(bufi, AL, Alo, m0, lda, k0);
        } else {
            stage_a_f32(bufi, Af, lda, k0);
        }
    };

    const int NT = K / 32;
    stage(0, 0);
    __syncthreads();
    int cur = 0;
    using FT = typename FragT<PREC>::T;
    for (int t = 0; t < NT; ++t) {
        if (t + 1 < NT) stage(cur ^ 1, t + 1);

        const u16* L = lds[cur];
        FT afh[4], afl[4], bfh[4], bfl[4];
#pragma unroll
        for (int i = 0; i < 4; ++i) {
            int ra = wm + i * 16 + fr;
            int rb = wn + i * 16 + fr;
            int oa = ra * 32 + ((kq ^ ((ra >> 1) & 3)) << 3);
            int ob = rb * 32 + ((kq ^ ((rb >> 1) & 3)) << 3);
            afh[i] = *(const FT*)(L + AH * 4096 + oa);
            bfh[i] = *(const FT*)(L + BH * 4096 + ob);
            if (TERMS == 3) {
                afl[i] = *(const FT*)(L + AL * 4096 + oa);
                bfl[i] = *(const FT*)(L + BL * 4096 + ob);
            }
        }
#pragma unroll
        for (int i = 0; i < 4; ++i)
#pragma unroll
            for (int j = 0; j < 4; ++j) {
                acc[i][j] = mfma16(afh[i], bfh[j], acc[i][j]);
                if (TERMS == 3) {
                    acc[i][j] = mfma16(afl[i], bfh[j], acc[i][j]);
                    acc[i][j] = mfma16(afh[i], bfl[j], acc[i][j]);
                }
            }
        __syncthreads();
        cur ^= 1;
    }

    long obase = (long)bz * sC + (long)kh * sKh;
    int fq = (lane >> 4) * 4;
#pragma unroll
    for (int i = 0; i < 4; ++i)
#pragma unroll
        for (int j = 0; j < 4; ++j)
#pragma unroll
            for (int g = 0; g < 4; ++g) {
                int row = m0 + wm + i * 16 + fq + g;
                int col = n0 + wn + j * 16 + fr;
                long idx = obase + (long)row * N + col;
                float v = acc[i][j][g];
                if constexpr (EPI == 1) {
                    u16 h2, l2;
                    split_bf(v, h2, l2);
                    Chi[idx] = h2;
                    Clo[idx] = l2;
                } else if constexpr (EPI == 2) {
                    float x = v + bias[col];
                    float t2 = __expf(2.f * x);
                    C[idx] = 1.f - 2.f * __builtin_amdgcn_rcpf(t2 + 1.f);
                } else {
                    Chi[idx] = __builtin_bit_cast(u16, (_Float16)v);
                }
            }
}

extern "C" void kernel_launch(void* const* d_in, const int* in_sizes, int n_in,
                              void* d_out, int out_size, void* d_ws, size_t ws_size,
                              hipStream_t stream) {
    const float* ht = (const float*)d_in[0];
    const float* hs = (const float*)d_in[1];
    const int* source = (const int*)d_in[2];
    const float* Wa = (const float*)d_in[3];
    const float* Wc = (const float*)d_in[4];
    const float* bias = (const float*)d_in[5];
    float* out = (float*)d_out;

    char* w = (char*)d_ws;
    size_t off = 0;
    auto alloc = [&](size_t bytes) -> void* {
        void* p = w + off;
        off += (bytes + 255) & ~(size_t)255;
        return p;
    };
    int* lens = (int*)alloc(256);
    u16* keysHi = (u16*)alloc((size_t)BB * TS * HH * 2);  // 16.78 MB (bf16)
    u16* keysLo = (u16*)alloc((size_t)BB * TS * HH * 2);
    u16* hsRHi = (u16*)alloc((size_t)BB * TS * HH * 2);   // dead after G1
    u16* hsRLo = (u16*)alloc((size_t)BB * TS * HH * 2);
    u16* hsTHi = (u16*)alloc((size_t)BB * HH * TS * 2);   // f16; G3's B
    u16* WaTHi = (u16*)alloc((size_t)HH * HH * 2);
    u16* WaTLo = (u16*)alloc((size_t)HH * HH * 2);
    u16* WcTHi = (u16*)alloc((size_t)2 * HH * OO * 2);    // f16; dedicated (4.2 MB)
    // total ~92.3 MB (<= 96.5 MB proven in round 1). Overlays:
    //   score H0|H1 -> hsRHi;  L0|L1 -> hsRLo   (hsR dead after G1)
    //   cHi f16 -> keysHi                        (keysHi dead after G2)
    //   htF f16 -> keysLo                        (keysLo dead after G2)
    u16* scoreH0 = hsRHi;
    u16* scoreH1 = hsRHi + (size_t)BB * TT * TS;
    u16* scoreL0 = hsRLo;
    u16* scoreL1 = hsRLo + (size_t)BB * TT * TS;
    u16* cHi = keysHi;
    u16* htF = keysLo;
    u16* prob = scoreH0;

    // prep1: hs_prep (8192) | WaT (1024) | lens (16) | WcT (2048) in one launch
    prep1_kernel<<<8192 + 1024 + 16 + 2048, 256, 0, stream>>>(
        hs, hsRHi, hsRLo, hsTHi, Wa, WaTHi, WaTLo, source, lens, Wc, WcTHi);

    // G1: keys = hs @ Wa  (bf16 3-term, 3-ring gemm_p, XCD swz) [measured 55 us]
    gemm_p<0, 3, 1, 0, 1, 1><<<256, 512, 0, stream>>>(
        hsRHi, hsRLo, nullptr, WaTHi, WaTLo,
        nullptr, keysHi, keysLo, nullptr,
        HH, HH, HH, HH, 0, 0, 0, 0);

    // G2: score[b] = ht[b] @ keys[b]^T  (bf16 3-term, 2-phase gemm_u, split-K=2)
    gemm_u<0, 1, 1, 3, 2, false><<<dim3(TS / 128, TT / 128, 2 * BB), 256, 0, stream>>>(
        nullptr, nullptr, ht, keysHi, keysLo,
        nullptr, scoreH0, scoreL0, nullptr,
        TT, TS, HH / 2, HH, HH,
        (long)TT * HH, (long)TS * HH, (long)TT * TS, (long)BB * TT * TS);

    // softmax (2048 blocks, 4 rows each) | htF f16 -> keysLo (4096 blocks), fused
    softmax_htf_kernel<<<2048 + 4096, 256, 0, stream>>>(
        scoreH0, scoreL0, scoreH1, scoreL1, lens, ht, htF);

    // G3: c[b] = prob[b] @ hs[b]  (f16 1-term, 2-phase gemm_u)
    gemm_u<1, 0, 3, 1, 1, false><<<dim3(HH / 128, TT / 128, BB), 256, 0, stream>>>(
        prob, nullptr, nullptr, hsTHi, nullptr,
        nullptr, cHi, nullptr, nullptr,
        TT, HH, TS, TS, TS,
        (long)TT * TS, (long)HH * TS, (long)TT * HH, 0);

    // G4: out = tanh(concat(c, ht) @ Wc + b)  (f16 1-term, gemm_p ACON, XCD swz)
    gemm_p<1, 1, 2, 1, 1, 1><<<256, 512, 0, stream>>>(
        cHi, nullptr, htF, WcTHi, nullptr,
        out, nullptr, nullptr, bias,
        OO, 2 * HH, HH, 2 * HH, 0, 0, 0, 0);
}